// Round 6
// baseline (361.480 us; speedup 1.0000x reference)
//
#include <hip/hip_runtime.h>
#include <hip/hip_bf16.h>

// ---------------------------------------------------------------------------
// DAWN block on MI355X.  Round 6:
//  - GEMM: T3 minimum-2-phase (double-buffered LDS, stage-before-compute,
//    ONE barrier per K-step) — staging latency hides under MFMA.
//  - fa: Q-tile 128 (4 waves x 32 q-rows), balanced per-CU mapping (34
//    key-tiles per CU exactly), XCD-chunked heads.
// ---------------------------------------------------------------------------

typedef __bf16 bf16_t;
typedef __bf16 bf16x8 __attribute__((ext_vector_type(8)));
typedef float f32x4 __attribute__((ext_vector_type(4)));

#define B_DIM 2
#define S_LEN 2048
#define D_DIM 1024
#define H_NUM 16
#define DH 64
#define N_NEU 8
#define R_DIM 256
#define KR_DIM 128
#define ROWS (B_DIM * S_LEN)   // 4096

static __device__ __forceinline__ void gl_lds16(const void* g, void* l)
{
    __builtin_amdgcn_global_load_lds(
        (__attribute__((address_space(1))) void*)(g),
        (__attribute__((address_space(3))) void*)(l), 16, 0, 0);
}

// ---------------------------------------------------------------------------
// Batched transpose-cast: in[z][I][J] f32 -> out[z][J][I] bf16.  block (32,8)
// ---------------------------------------------------------------------------
__global__ __launch_bounds__(256)
void tcast_kernel(const float* __restrict__ in, bf16_t* __restrict__ out, int I, int J)
{
    __shared__ float t[32][33];
    const int bJ = blockIdx.x * 32, bI = blockIdx.y * 32;
    const size_t boff = (size_t)blockIdx.z * I * J;
    const int tx = threadIdx.x, ty = threadIdx.y;
#pragma unroll
    for (int i = 0; i < 4; i++)
        t[ty * 4 + i][tx] = in[boff + (size_t)(bI + ty * 4 + i) * J + bJ + tx];
    __syncthreads();
#pragma unroll
    for (int i = 0; i < 4; i++)
        out[boff + (size_t)(bJ + ty * 4 + i) * I + bI + tx] = (bf16_t)t[tx][ty * 4 + i];
}

// bf16 transpose: in[z][I][J] -> out[z][J][I].  block (32,8)
__global__ __launch_bounds__(256)
void tbf_kernel(const bf16_t* __restrict__ in, bf16_t* __restrict__ out, int I, int J)
{
    __shared__ bf16_t t[32][33];
    const int bJ = blockIdx.x * 32, bI = blockIdx.y * 32;
    const size_t boff = (size_t)blockIdx.z * I * J;
    const int tx = threadIdx.x, ty = threadIdx.y;
#pragma unroll
    for (int i = 0; i < 4; i++)
        t[ty * 4 + i][tx] = in[boff + (size_t)(bI + ty * 4 + i) * J + bJ + tx];
    __syncthreads();
#pragma unroll
    for (int i = 0; i < 4; i++)
        out[boff + (size_t)(bJ + ty * 4 + i) * I + bI + tx] = t[tx][ty * 4 + i];
}

// plain cast fp32 -> bf16 (vectorized by 4)
__global__ __launch_bounds__(256)
void cast_kernel(const float* __restrict__ in, bf16_t* __restrict__ out, int n4)
{
    int i = blockIdx.x * 256 + threadIdx.x;
    if (i < n4) {
        float4 v = ((const float4*)in)[i];
        bf16_t* op = out + (size_t)i * 4;
        op[0] = (bf16_t)v.x; op[1] = (bf16_t)v.y; op[2] = (bf16_t)v.z; op[3] = (bf16_t)v.w;
    }
}

// ---------------------------------------------------------------------------
// LayerNorm over D=1024, one row per block. fp32 in, bf16 out.
// ---------------------------------------------------------------------------
__global__ __launch_bounds__(256)
void ln_kernel(const float* __restrict__ x, const float* __restrict__ g,
               const float* __restrict__ beta, bf16_t* __restrict__ out)
{
    __shared__ float red[4];
    const int row = blockIdx.x;
    const int tid = threadIdx.x;
    float4 v = *(const float4*)&x[(size_t)row * D_DIM + tid * 4];

    float s = v.x + v.y + v.z + v.w;
#pragma unroll
    for (int o = 32; o; o >>= 1) s += __shfl_down(s, o);
    if ((tid & 63) == 0) red[tid >> 6] = s;
    __syncthreads();
    float mean = (red[0] + red[1] + red[2] + red[3]) * (1.f / D_DIM);
    __syncthreads();

    float dx = v.x - mean, dy = v.y - mean, dz = v.z - mean, dw = v.w - mean;
    float q = dx * dx + dy * dy + dz * dz + dw * dw;
#pragma unroll
    for (int o = 32; o; o >>= 1) q += __shfl_down(q, o);
    if ((tid & 63) == 0) red[tid >> 6] = q;
    __syncthreads();
    float var = (red[0] + red[1] + red[2] + red[3]) * (1.f / D_DIM);
    float rstd = rsqrtf(var + 1e-5f);

    float4 gv = *(const float4*)&g[tid * 4];
    float4 bv = *(const float4*)&beta[tid * 4];
    bf16_t* op = out + (size_t)row * D_DIM + tid * 4;
    op[0] = (bf16_t)(dx * rstd * gv.x + bv.x);
    op[1] = (bf16_t)(dy * rstd * gv.y + bv.y);
    op[2] = (bf16_t)(dz * rstd * gv.z + bv.z);
    op[3] = (bf16_t)(dw * rstd * gv.w + bv.w);
}

// ---------------------------------------------------------------------------
// LN2 with fused split-K reduce + residual:  sum = x + P0 + P1 -> outf (fp32),
// then LN(sum) -> bf16 outn.
// ---------------------------------------------------------------------------
__global__ __launch_bounds__(256)
void ln2x_kernel(const float* __restrict__ x, const float* __restrict__ P0,
                 const float* __restrict__ P1, const float* __restrict__ g,
                 const float* __restrict__ beta, float* __restrict__ outf,
                 bf16_t* __restrict__ outn)
{
    __shared__ float red[4];
    const int row = blockIdx.x;
    const int tid = threadIdx.x;
    const size_t base = (size_t)row * D_DIM + tid * 4;
    float4 v  = *(const float4*)&x[base];
    float4 p0 = *(const float4*)&P0[base];
    float4 p1 = *(const float4*)&P1[base];
    v.x += p0.x + p1.x; v.y += p0.y + p1.y; v.z += p0.z + p1.z; v.w += p0.w + p1.w;
    *(float4*)&outf[base] = v;

    float s = v.x + v.y + v.z + v.w;
#pragma unroll
    for (int o = 32; o; o >>= 1) s += __shfl_down(s, o);
    if ((tid & 63) == 0) red[tid >> 6] = s;
    __syncthreads();
    float mean = (red[0] + red[1] + red[2] + red[3]) * (1.f / D_DIM);
    __syncthreads();

    float dx = v.x - mean, dy = v.y - mean, dz = v.z - mean, dw = v.w - mean;
    float q = dx * dx + dy * dy + dz * dz + dw * dw;
#pragma unroll
    for (int o = 32; o; o >>= 1) q += __shfl_down(q, o);
    if ((tid & 63) == 0) red[tid >> 6] = q;
    __syncthreads();
    float var = (red[0] + red[1] + red[2] + red[3]) * (1.f / D_DIM);
    float rstd = rsqrtf(var + 1e-5f);

    float4 gv = *(const float4*)&g[tid * 4];
    float4 bv = *(const float4*)&beta[tid * 4];
    bf16_t* op = outn + base;
    op[0] = (bf16_t)(dx * rstd * gv.x + bv.x);
    op[1] = (bf16_t)(dy * rstd * gv.y + bv.y);
    op[2] = (bf16_t)(dz * rstd * gv.z + bv.z);
    op[3] = (bf16_t)(dw * rstd * gv.w + bv.w);
}

// ---------------------------------------------------------------------------
// Fused weighted-sum for Q/K/V: reads y row once, writes sq, sk, sv.
// ---------------------------------------------------------------------------
__global__ __launch_bounds__(256)
void wsf_kernel(const bf16_t* __restrict__ y,
                const float* __restrict__ wfQ, const float* __restrict__ wrQ,
                const float* __restrict__ wfK, const float* __restrict__ wrK,
                const float* __restrict__ wfV, const float* __restrict__ wrV,
                bf16_t* __restrict__ sq, bf16_t* __restrict__ sk, bf16_t* __restrict__ sv)
{
    const int r = threadIdx.x;
    const int row = blockIdx.x;
    const bf16_t* yrow = y + (size_t)row * 4096;
    const float* fQ = wfQ + row * N_NEU;
    const float* fK = wfK + row * N_NEU;
    const float* fV = wfV + row * N_NEU;
    float aQ = 0.f, aK = 0.f, aV = 0.f;
#pragma unroll
    for (int n = 0; n < N_NEU; n++) {
        float yq = (float)yrow[n * R_DIM + r];
        float yv = (float)yrow[2048 + n * R_DIM + r];
        aQ += fQ[n] * yq;
        aK += fK[n] * yq;
        aV += fV[n] * yv;
    }
    const float* rQ = wrQ + row * N_NEU;
    const float* rK = wrK + row * N_NEU;
    const float* rV = wrV + row * N_NEU;
    const size_t rb = (size_t)row * 2048;
#pragma unroll
    for (int n = 0; n < N_NEU; n++) {
        sq[rb + n * R_DIM + r] = (bf16_t)(rQ[n] * aQ);
        sk[rb + n * R_DIM + r] = (bf16_t)(rK[n] * aK);
        sv[rb + n * R_DIM + r] = (bf16_t)(rV[n] * aV);
    }
}

// know-path ws with fused split-K reduce: y = P0+P1 (fp32 partials), KR=128.
__global__ __launch_bounds__(256)
void ws2_kernel(const float* __restrict__ P0, const float* __restrict__ P1,
                const float* __restrict__ wf, const float* __restrict__ wr,
                bf16_t* __restrict__ sout)
{
    const int lr = threadIdx.x >> 7;
    const int r  = threadIdx.x & 127;
    const int row = blockIdx.x * 2 + lr;
    const size_t rb = (size_t)row * (N_NEU * KR_DIM);
    const float* wfp = wf + row * N_NEU;
    const float* wrp = wr + row * N_NEU;
    float acc = 0.f;
#pragma unroll
    for (int n = 0; n < N_NEU; n++) {
        size_t i = rb + n * KR_DIM + r;
        acc += wfp[n] * (P0[i] + P1[i]);
    }
    bf16_t* srow = sout + rb;
#pragma unroll
    for (int n = 0; n < N_NEU; n++) srow[n * KR_DIM + r] = (bf16_t)(wrp[n] * acc);
}

// ---------------------------------------------------------------------------
// GEMM, 2-phase double-buffered (T3 minimum recipe):
//   prologue: STAGE(buf0); barrier
//   loop:     STAGE(buf^1, next) ; ds_read+MFMA(buf) ; barrier ; flip
// One barrier per K-step; staging latency hides under MFMA.
// C[M,N] = A[M,K] @ Bsel[N,K]^T.  128x128 tile, BK=32.
// EPI=0: bf16 C.  EPI=1: fp32 C = acc + resid.  EPI=2: fp32 partial per
// blockIdx.z (split-K=2).
// ---------------------------------------------------------------------------
template<int EPI>
__global__ __launch_bounds__(256)
void gemm_kernel(const bf16_t* __restrict__ A, const bf16_t* __restrict__ Bt,
                 const bf16_t* __restrict__ Bt2, int splitMy,
                 void* Cout, const float* resid, int M, int N, int K)
{
    __shared__ bf16_t As[2][128][32];
    __shared__ bf16_t Bs[2][128][32];
    const int tid = threadIdx.x;
    const int l = tid & 63, w = tid >> 6;
    const int wr = w >> 1, wc = w & 1;

    // XCD-chunked swizzle (bijective when grid multiple of 8)
    const int nbxy = gridDim.x * gridDim.y;
    int bid = blockIdx.y * gridDim.x + blockIdx.x;
    if ((nbxy & 7) == 0) bid = (bid & 7) * (nbxy >> 3) + (bid >> 3);
    const int bx = bid % gridDim.x, by = bid / gridDim.x;

    const int m0 = by * 128, n0 = bx * 128;
    const bf16_t* Bsel = (by < splitMy) ? Bt : Bt2;

    int kbeg = 0, kend = K;
    if constexpr (EPI == 2) { const int half = K >> 1; kbeg = blockIdx.z * half; kend = kbeg + half; }

    const int srow = l >> 2;
    const int scol = (l & 3) * 8;
    const bf16_t* Ag0 = A    + (size_t)(m0 + w * 32 + srow) * K + scol;
    const bf16_t* Ag1 = Ag0 + (size_t)16 * K;
    const bf16_t* Bg0 = Bsel + (size_t)(n0 + w * 32 + srow) * K + scol;
    const bf16_t* Bg1 = Bg0 + (size_t)16 * K;

    auto stage = [&](int buf, int k0) {
        char* Asb = (char*)&As[buf][0][0] + w * 2048;
        char* Bsb = (char*)&Bs[buf][0][0] + w * 2048;
        gl_lds16(Ag0 + k0, Asb);
        gl_lds16(Ag1 + k0, Asb + 1024);
        gl_lds16(Bg0 + k0, Bsb);
        gl_lds16(Bg1 + k0, Bsb + 1024);
    };

    f32x4 acc[4][4];
    const f32x4 zero = {0.f, 0.f, 0.f, 0.f};
#pragma unroll
    for (int i = 0; i < 4; i++)
#pragma unroll
        for (int j = 0; j < 4; j++) acc[i][j] = zero;

    const int fr = l & 15;
    const int fk = (l >> 4) * 8;

    // prologue
    stage(0, kbeg);
    __syncthreads();          // drains vmcnt(0): buf0 ready

    int cur = 0;
    for (int k0 = kbeg; k0 < kend; k0 += 32) {
        if (k0 + 32 < kend) stage(cur ^ 1, k0 + 32);   // prefetch next tile

        bf16x8 af[4], bv[4];
#pragma unroll
        for (int i = 0; i < 4; i++) af[i] = *(const bf16x8*)&As[cur][wr * 64 + i * 16 + fr][fk];
#pragma unroll
        for (int i = 0; i < 4; i++) bv[i] = *(const bf16x8*)&Bs[cur][wc * 64 + i * 16 + fr][fk];
        __builtin_amdgcn_s_setprio(1);
#pragma unroll
        for (int mi = 0; mi < 4; mi++)
#pragma unroll
            for (int ni = 0; ni < 4; ni++)
                acc[mi][ni] = __builtin_amdgcn_mfma_f32_16x16x32_bf16(af[mi], bv[ni], acc[mi][ni], 0, 0, 0);
        __builtin_amdgcn_s_setprio(0);
        __syncthreads();       // drains vmcnt(0)+lgkmcnt(0): next buf ready, reads done
        cur ^= 1;
    }

    const int orow = (l >> 4) * 4;
    const int ocol = l & 15;
#pragma unroll
    for (int mi = 0; mi < 4; mi++)
#pragma unroll
        for (int ni = 0; ni < 4; ni++)
#pragma unroll
            for (int j = 0; j < 4; j++) {
                int row = m0 + wr * 64 + mi * 16 + orow + j;
                int col = n0 + wc * 64 + ni * 16 + ocol;
                size_t idx = (size_t)row * N + col;
                if constexpr (EPI == 0) {
                    ((bf16_t*)Cout)[idx] = (bf16_t)acc[mi][ni][j];
                } else if constexpr (EPI == 1) {
                    ((float*)Cout)[idx] = acc[mi][ni][j] + resid[idx];
                } else {
                    ((float*)Cout)[(size_t)blockIdx.z * M * N + idx] = acc[mi][ni][j];
                }
            }
}

// ---------------------------------------------------------------------------
// Causal flash attention.  Q/K/O: [B*S][1024] bf16 (head h = cols h*64..+64).
// Vt: [B][1024][2048] bf16 (pre-transposed V).
// 512 blocks, Q-tile 128 (4 waves x 32 q-rows).  Balanced XCD-chunked map:
//   xcd=bid&7, slot=bid>>3 (0..63), head=slot&3, j=slot>>2 (0..15),
//   qb = j<8 ? j : 23-j.
// CU c gets slots {c, c+32} -> qb pair (j, 15-j) -> exactly 34 key-tiles/CU,
// same head per CU (K/V L1/L2-warm).  KVBLK=64, T14 issue-early staging,
// exp2 softmax, defer-max (T13), setprio (T5).
// ---------------------------------------------------------------------------
__global__ __launch_bounds__(256)
void fa_kernel(const bf16_t* __restrict__ Q, const bf16_t* __restrict__ K,
               const bf16_t* __restrict__ Vt, bf16_t* __restrict__ O)
{
    __shared__ bf16_t Ks[64][72];
    __shared__ bf16_t Vs[64][72];
    __shared__ bf16_t Ps[4][32][72];

    const int tid = threadIdx.x;
    const int l = tid & 63, w = tid >> 6;

    const int bid  = blockIdx.x;
    const int xcd  = bid & 7;
    const int slot = bid >> 3;          // 0..63
    const int head = slot & 3;
    const int j6   = slot >> 2;         // 0..15
    const int qb   = (j6 < 8) ? j6 : (23 - j6);
    const int bh   = xcd * 4 + head;
    const int b = bh >> 4, h = bh & 15;
    const int q0 = qb * 128;

    const bf16_t* Qp = Q + (size_t)b * S_LEN * D_DIM + h * DH;
    const bf16_t* Kp = K + (size_t)b * S_LEN * D_DIM + h * DH;
    const bf16_t* Vp = Vt + (size_t)b * D_DIM * S_LEN + (size_t)h * DH * S_LEN;

    const int fr = l & 15, fg = l >> 4, fk = fg * 8;

    // Q fragments: 2 row-frags x 2 k-steps
    bf16x8 qf[2][2];
#pragma unroll
    for (int mi = 0; mi < 2; mi++)
#pragma unroll
        for (int ks = 0; ks < 2; ks++)
            qf[mi][ks] = *(const bf16x8*)(Qp + (size_t)(q0 + w * 32 + mi * 16 + fr) * D_DIM + ks * 32 + fk);

    const f32x4 zero = {0.f, 0.f, 0.f, 0.f};
    f32x4 o[2][4];
    float m_r[2][4], l_r[2][4];
#pragma unroll
    for (int mi = 0; mi < 2; mi++)
#pragma unroll
        for (int j = 0; j < 4; j++) { o[mi][j] = zero; m_r[mi][j] = -1e30f; l_r[mi][j] = 0.f; }

    const int srow = tid >> 2;
    const int scol = (tid & 3) * 16;
    const bf16_t* Kst = Kp + (size_t)srow * D_DIM + scol;
    const bf16_t* Vst = Vp + (size_t)srow * S_LEN + scol;

    const int nt = q0 / 64 + 2;
    const float C_LOG2 = 0.125f * 1.44269504f;   // 1/sqrt(DH) * log2(e)

    // prologue: issue loads for tile 0
    uint4 kva = *(const uint4*)(Kst);
    uint4 kvb = *(const uint4*)(Kst + 8);
    uint4 vva = *(const uint4*)(Vst);
    uint4 vvb = *(const uint4*)(Vst + 8);

    const int wq_hi = q0 + w * 32 + 31;

    for (int t = 0; t < nt; t++) {
        const int k0 = t * 64;
        __syncthreads();              // previous tile's reads complete
        *(uint4*)&Ks[srow][scol]     = kva;
        *(uint4*)&Ks[srow][scol + 8] = kvb;
        *(uint4*)&Vs[srow][scol]     = vva;
        *(uint4*)&Vs[srow][scol + 8] = vvb;
        __syncthreads();

        if (t + 1 < nt) {             // T14: issue next tile's loads now
            const int kn = k0 + 64;
            kva = *(const uint4*)(Kst + (size_t)kn * D_DIM);
            kvb = *(const uint4*)(Kst + (size_t)kn * D_DIM + 8);
            vva = *(const uint4*)(Vst + kn);
            vvb = *(const uint4*)(Vst + kn + 8);
        }

        if (k0 > wq_hi) continue;     // tile entirely above this wave's rows

        // ---- QK^T: 32 q-rows x 64 keys ----
        f32x4 sc[2][4];
#pragma unroll
        for (int mi = 0; mi < 2; mi++)
#pragma unroll
            for (int ni = 0; ni < 4; ni++) sc[mi][ni] = zero;
        __builtin_amdgcn_s_setprio(1);
#pragma unroll
        for (int ks = 0; ks < 2; ks++) {
#pragma unroll
            for (int ni = 0; ni < 4; ni++) {
                bf16x8 kf = *(const bf16x8*)&Ks[ni * 16 + fr][ks * 32 + fk];
#pragma unroll
                for (int mi = 0; mi < 2; mi++)
                    sc[mi][ni] = __builtin_amdgcn_mfma_f32_16x16x32_bf16(qf[mi][ks], kf, sc[mi][ni], 0, 0, 0);
            }
        }
        __builtin_amdgcn_s_setprio(0);

        // ---- scale to log2 domain + causal mask ----
        float p[2][4][4];
#pragma unroll
        for (int mi = 0; mi < 2; mi++)
#pragma unroll
            for (int ni = 0; ni < 4; ni++) {
                const int key = k0 + ni * 16 + fr;
#pragma unroll
                for (int j = 0; j < 4; j++) {
                    const int qg = q0 + w * 32 + mi * 16 + fg * 4 + j;
                    p[mi][ni][j] = (key <= qg) ? sc[mi][ni][j] * C_LOG2 : -1e30f;
                }
            }

        // ---- online softmax (exp2 domain), defer-max (T13) ----
#pragma unroll
        for (int mi = 0; mi < 2; mi++)
#pragma unroll
            for (int j = 0; j < 4; j++) {
                float rmax = fmaxf(fmaxf(p[mi][0][j], p[mi][1][j]), fmaxf(p[mi][2][j], p[mi][3][j]));
#pragma unroll
                for (int d = 1; d < 16; d <<= 1) rmax = fmaxf(rmax, __shfl_xor(rmax, d));
                if (rmax > m_r[mi][j] + 8.f) {
                    float scale = exp2f(m_r[mi][j] - rmax);
                    l_r[mi][j] *= scale;
#pragma unroll
                    for (int nc = 0; nc < 4; nc++) o[mi][nc][j] *= scale;
                    m_r[mi][j] = rmax;
                }
                float rsum = 0.f;
#pragma unroll
                for (int ni = 0; ni < 4; ni++) {
                    float e = exp2f(p[mi][ni][j] - m_r[mi][j]);   // <= 2^8
                    p[mi][ni][j] = e; rsum += e;
                }
#pragma unroll
                for (int d = 1; d < 16; d <<= 1) rsum += __shfl_xor(rsum, d);
                l_r[mi][j] += rsum;
            }

        // ---- P -> A-layout via per-wave LDS bounce ----
#pragma unroll
        for (int mi = 0; mi < 2; mi++)
#pragma unroll
            for (int ni = 0; ni < 4; ni++)
#pragma unroll
                for (int j = 0; j < 4; j++)
                    Ps[w][mi * 16 + fg * 4 + j][ni * 16 + fr] = (bf16_t)p[mi][ni][j];

        // ---- PV ----
        __builtin_amdgcn_s_setprio(1);
#pragma unroll
        for (int ks = 0; ks < 2; ks++) {
            bf16x8 pa[2];
#pragma unroll
            for (int mi = 0; mi < 2; mi++)
                pa[mi] = *(const bf16x8*)&Ps[w][mi * 16 + fr][ks * 32 + fk];
#pragma unroll
            for (int nc = 0; nc < 4; nc++) {
                bf16x8 vf = *(const bf16x8*)&Vs[nc * 16 + fr][ks * 32 + fk];
#pragma unroll
                for (int mi = 0; mi < 2; mi++)
                    o[mi][nc] = __builtin_amdgcn_mfma_f32_16x16x32_bf16(pa[mi], vf, o[mi][nc], 0, 0, 0);
            }
        }
        __builtin_amdgcn_s_setprio(0);
    }

    // ---- epilogue ----
#pragma unroll
    for (int mi = 0; mi < 2; mi++)
#pragma unroll
        for (int j = 0; j < 4; j++) {
            const float inv = 1.f / l_r[mi][j];
            const int q = q0 + w * 32 + mi * 16 + fg * 4 + j;
            bf16_t* op = O + (size_t)(b * S_LEN + q) * D_DIM + h * DH;
#pragma unroll
            for (int nc = 0; nc < 4; nc++)
                op[nc * 16 + fr] = (bf16_t)(o[mi][nc][j] * inv);
        }
}

// ---------------------------------------------------------------------------
extern "C" void kernel_launch(void* const* d_in, const int* in_sizes, int n_in,
                              void* d_out, int out_size, void* d_ws, size_t ws_size,
                              hipStream_t stream)
{
    const float* x      = (const float*)d_in[0];
    const float* fqk_wQ = (const float*)d_in[1];
    const float* fqk_wK = (const float*)d_in[2];
    const float* fv_w   = (const float*)d_in[3];
    const float* rqk_wQ = (const float*)d_in[4];
    const float* rqk_wK = (const float*)d_in[5];
    const float* rv_w   = (const float*)d_in[6];
    const float* fkn_w  = (const float*)d_in[7];
    const float* rkn_w  = (const float*)d_in[8];
    const float* f_qk   = (const float*)d_in[9];
    const float* f_v    = (const float*)d_in[10];
    const float* r_qk   = (const float*)d_in[11];
    const float* r_v    = (const float*)d_in[12];
    const float* f_know = (const float*)d_in[13];
    const float* r_know = (const float*)d_in[14];
    const float* W_O    = (const float*)d_in[15];
    const float* ln1g   = (const float*)d_in[16];
    const float* ln1b   = (const float*)d_in[17];
    const float* ln2g   = (const float*)d_in[18];
    const float* ln2b   = (const float*)d_in[19];
    float* out_f = (float*)d_out;
    (void)ws_size; (void)in_sizes; (void)n_in; (void)out_size;

    // ---- workspace layout (reused slots) ----
    char* ws = (char*)d_ws;
    const size_t MB = 1024 * 1024;
    bf16_t* rqkT   = (bf16_t*)(ws + 0 * MB);    // [1024][2048]  4MB
    bf16_t* rvT    = (bf16_t*)(ws + 4 * MB);    // [1024][2048]  4MB
    bf16_t* rknT   = (bf16_t*)(ws + 8 * MB);    // [1024][1024]  2MB
    bf16_t* woB    = (bf16_t*)(ws + 10 * MB);   // [1024][1024]  2MB
    bf16_t* fknT   = (bf16_t*)(ws + 12 * MB);   // [1024][1024]  2MB
    bf16_t* buf_nx = (bf16_t*)(ws + 14 * MB);   // 8MB: nx -> Vt -> nx2
    bf16_t* buf_y  = (bf16_t*)(ws + 22 * MB);   // 32MB: y[4096][4096] -> QKV[12288][1024]
    char*   buf_s  = ws + 54 * MB;              // 48MB
    bf16_t* fqkT   = (bf16_t*)(buf_s);               // [2048][1024] 4MB (pre-ws only)
    bf16_t* fvT    = (bf16_t*)(buf_s + 4 * MB);      // contiguous -> N=4096 B
    bf16_t* s_q    = (bf16_t*)(buf_s);               // [12288][2048] grouped A
    bf16_t* s_k    = (bf16_t*)(buf_s) + (size_t)4096 * 2048;
    bf16_t* s_v    = (bf16_t*)(buf_s) + (size_t)8192 * 2048;
    bf16_t* attn   = (bf16_t*)(buf_s);               // [4096][1024] 8MB
    float*  P0     = (float*)(buf_s + 16 * MB);      // W_O split-K partials 2x16MB
    float*  P0k    = (float*)(buf_s);                // know split-K partials
    float*  P1k    = (float*)(buf_s + 16 * MB);
    bf16_t* sk2    = (bf16_t*)(buf_s + 32 * MB);     // [4096][1024] 8MB
    bf16_t* Qb     = buf_y;                          // QKV contiguous [12288][1024]
    bf16_t* Kb     = buf_y + (size_t)4096 * 1024;
    bf16_t* Vb     = buf_y + (size_t)8192 * 1024;
    bf16_t* Vt     = buf_nx;                         // [2][1024][2048]

    const dim3 blk256(256), blkT(32, 8);

    // ---- weight conversion ----
    tcast_kernel<<<dim3(R_DIM / 32, D_DIM / 32, N_NEU), blkT, 0, stream>>>(f_qk, fqkT, D_DIM, R_DIM);
    tcast_kernel<<<dim3(R_DIM / 32, D_DIM / 32, N_NEU), blkT, 0, stream>>>(f_v, fvT, D_DIM, R_DIM);
    tcast_kernel<<<dim3(KR_DIM / 32, D_DIM / 32, N_NEU), blkT, 0, stream>>>(f_know, fknT, D_DIM, KR_DIM);
    tcast_kernel<<<dim3(D_DIM / 32, 2048 / 32, 1), blkT, 0, stream>>>(r_qk, rqkT, 2048, D_DIM);
    tcast_kernel<<<dim3(D_DIM / 32, 2048 / 32, 1), blkT, 0, stream>>>(r_v, rvT, 2048, D_DIM);
    tcast_kernel<<<dim3(D_DIM / 32, 1024 / 32, 1), blkT, 0, stream>>>(r_know, rknT, 1024, D_DIM);
    cast_kernel<<<dim3(1024 * 1024 / 4 / 256), blk256, 0, stream>>>(W_O, woB, 1024 * 1024 / 4);

    // ---- LN1 ----
    ln_kernel<<<dim3(ROWS), blk256, 0, stream>>>(x, ln1g, ln1b, buf_nx);

    // ---- fused feature GEMM: y[4096][4096] = nx @ [fqkT;fvT]^T ----
    gemm_kernel<0><<<dim3(32, 32), blk256, 0, stream>>>(buf_nx, fqkT, fqkT, 1 << 30, buf_y, nullptr, 4096, 4096, 1024);

    // ---- fused weighted sums -> sq|sk|sv [12288][2048] ----
    wsf_kernel<<<dim3(ROWS), blk256, 0, stream>>>(buf_y, fqk_wQ, rqk_wQ, fqk_wK, rqk_wK, fv_w, rv_w, s_q, s_k, s_v);

    // ---- grouped restore GEMM: QKV[12288][1024] (768 blocks, B-select) ----
    gemm_kernel<0><<<dim3(8, 96), blk256, 0, stream>>>((bf16_t*)buf_s, rqkT, rvT, 64, buf_y, nullptr, 12288, 1024, 2048);

    // ---- V -> Vt ----
    tbf_kernel<<<dim3(D_DIM / 32, S_LEN / 32, B_DIM), blkT, 0, stream>>>(Vb, Vt, S_LEN, D_DIM);

    // ---- attention (512 blocks, Q-tile 128, balanced mapping) ----
    fa_kernel<<<dim3(512), blk256, 0, stream>>>(Qb, Kb, Vt, attn);

    // ---- W_O split-K=2: partials P0/P1 (512 blocks) ----
    gemm_kernel<2><<<dim3(8, 32, 2), blk256, 0, stream>>>(attn, woB, woB, 1 << 30, P0, nullptr, 4096, 1024, 1024);

    // ---- LN2 fused: d_out = x + P0 + P1; nx2 = LN(d_out) ----
    ln2x_kernel<<<dim3(ROWS), blk256, 0, stream>>>(x, P0, P0 + (size_t)4096 * 1024, ln2g, ln2b, out_f, buf_nx);

    // ---- know feature split-K=2: partials P0k/P1k (512 blocks) ----
    gemm_kernel<2><<<dim3(8, 32, 2), blk256, 0, stream>>>(buf_nx, fknT, fknT, 1 << 30, P0k, nullptr, 4096, 1024, 1024);

    // ---- know ws (fused reduce) -> sk2 ----
    ws2_kernel<<<dim3(ROWS / 2), blk256, 0, stream>>>(P0k, P1k, fkn_w, rkn_w, sk2);

    // ---- out = sk2 @ rknT^T + x2 -> d_out ----
    gemm_kernel<1><<<dim3(8, 32), blk256, 0, stream>>>(sk2, rknT, rknT, 1 << 30, d_out, out_f, 4096, 1024, 1024);
}

// Round 7
// 330.420 us; speedup vs baseline: 1.0940x; 1.0940x over previous
//
#include <hip/hip_runtime.h>
#include <hip/hip_bf16.h>

// ---------------------------------------------------------------------------
// DAWN block on MI355X.  Round 7:
//  - fa: revert to R5 structure (Q-tile 64, 1024 blocks, balanced per-CU map)
//        + l-sum via MFMA ones-column (kills the 16-shfl rsum reduction)
//  - GEMM: R6 2-phase double-buffered (kept, −7% confirmed)
// ---------------------------------------------------------------------------

typedef __bf16 bf16_t;
typedef __bf16 bf16x8 __attribute__((ext_vector_type(8)));
typedef float f32x4 __attribute__((ext_vector_type(4)));

#define B_DIM 2
#define S_LEN 2048
#define D_DIM 1024
#define H_NUM 16
#define DH 64
#define N_NEU 8
#define R_DIM 256
#define KR_DIM 128
#define ROWS (B_DIM * S_LEN)   // 4096

static __device__ __forceinline__ void gl_lds16(const void* g, void* l)
{
    __builtin_amdgcn_global_load_lds(
        (__attribute__((address_space(1))) void*)(g),
        (__attribute__((address_space(3))) void*)(l), 16, 0, 0);
}

// ---------------------------------------------------------------------------
// Batched transpose-cast: in[z][I][J] f32 -> out[z][J][I] bf16.  block (32,8)
// ---------------------------------------------------------------------------
__global__ __launch_bounds__(256)
void tcast_kernel(const float* __restrict__ in, bf16_t* __restrict__ out, int I, int J)
{
    __shared__ float t[32][33];
    const int bJ = blockIdx.x * 32, bI = blockIdx.y * 32;
    const size_t boff = (size_t)blockIdx.z * I * J;
    const int tx = threadIdx.x, ty = threadIdx.y;
#pragma unroll
    for (int i = 0; i < 4; i++)
        t[ty * 4 + i][tx] = in[boff + (size_t)(bI + ty * 4 + i) * J + bJ + tx];
    __syncthreads();
#pragma unroll
    for (int i = 0; i < 4; i++)
        out[boff + (size_t)(bJ + ty * 4 + i) * I + bI + tx] = (bf16_t)t[tx][ty * 4 + i];
}

// bf16 transpose: in[z][I][J] -> out[z][J][I].  block (32,8)
__global__ __launch_bounds__(256)
void tbf_kernel(const bf16_t* __restrict__ in, bf16_t* __restrict__ out, int I, int J)
{
    __shared__ bf16_t t[32][33];
    const int bJ = blockIdx.x * 32, bI = blockIdx.y * 32;
    const size_t boff = (size_t)blockIdx.z * I * J;
    const int tx = threadIdx.x, ty = threadIdx.y;
#pragma unroll
    for (int i = 0; i < 4; i++)
        t[ty * 4 + i][tx] = in[boff + (size_t)(bI + ty * 4 + i) * J + bJ + tx];
    __syncthreads();
#pragma unroll
    for (int i = 0; i < 4; i++)
        out[boff + (size_t)(bJ + ty * 4 + i) * I + bI + tx] = t[tx][ty * 4 + i];
}

// plain cast fp32 -> bf16 (vectorized by 4)
__global__ __launch_bounds__(256)
void cast_kernel(const float* __restrict__ in, bf16_t* __restrict__ out, int n4)
{
    int i = blockIdx.x * 256 + threadIdx.x;
    if (i < n4) {
        float4 v = ((const float4*)in)[i];
        bf16_t* op = out + (size_t)i * 4;
        op[0] = (bf16_t)v.x; op[1] = (bf16_t)v.y; op[2] = (bf16_t)v.z; op[3] = (bf16_t)v.w;
    }
}

// ---------------------------------------------------------------------------
// LayerNorm over D=1024, one row per block. fp32 in, bf16 out.
// ---------------------------------------------------------------------------
__global__ __launch_bounds__(256)
void ln_kernel(const float* __restrict__ x, const float* __restrict__ g,
               const float* __restrict__ beta, bf16_t* __restrict__ out)
{
    __shared__ float red[4];
    const int row = blockIdx.x;
    const int tid = threadIdx.x;
    float4 v = *(const float4*)&x[(size_t)row * D_DIM + tid * 4];

    float s = v.x + v.y + v.z + v.w;
#pragma unroll
    for (int o = 32; o; o >>= 1) s += __shfl_down(s, o);
    if ((tid & 63) == 0) red[tid >> 6] = s;
    __syncthreads();
    float mean = (red[0] + red[1] + red[2] + red[3]) * (1.f / D_DIM);
    __syncthreads();

    float dx = v.x - mean, dy = v.y - mean, dz = v.z - mean, dw = v.w - mean;
    float q = dx * dx + dy * dy + dz * dz + dw * dw;
#pragma unroll
    for (int o = 32; o; o >>= 1) q += __shfl_down(q, o);
    if ((tid & 63) == 0) red[tid >> 6] = q;
    __syncthreads();
    float var = (red[0] + red[1] + red[2] + red[3]) * (1.f / D_DIM);
    float rstd = rsqrtf(var + 1e-5f);

    float4 gv = *(const float4*)&g[tid * 4];
    float4 bv = *(const float4*)&beta[tid * 4];
    bf16_t* op = out + (size_t)row * D_DIM + tid * 4;
    op[0] = (bf16_t)(dx * rstd * gv.x + bv.x);
    op[1] = (bf16_t)(dy * rstd * gv.y + bv.y);
    op[2] = (bf16_t)(dz * rstd * gv.z + bv.z);
    op[3] = (bf16_t)(dw * rstd * gv.w + bv.w);
}

// ---------------------------------------------------------------------------
// LN2 with fused split-K reduce + residual:  sum = x + P0 + P1 -> outf (fp32),
// then LN(sum) -> bf16 outn.
// ---------------------------------------------------------------------------
__global__ __launch_bounds__(256)
void ln2x_kernel(const float* __restrict__ x, const float* __restrict__ P0,
                 const float* __restrict__ P1, const float* __restrict__ g,
                 const float* __restrict__ beta, float* __restrict__ outf,
                 bf16_t* __restrict__ outn)
{
    __shared__ float red[4];
    const int row = blockIdx.x;
    const int tid = threadIdx.x;
    const size_t base = (size_t)row * D_DIM + tid * 4;
    float4 v  = *(const float4*)&x[base];
    float4 p0 = *(const float4*)&P0[base];
    float4 p1 = *(const float4*)&P1[base];
    v.x += p0.x + p1.x; v.y += p0.y + p1.y; v.z += p0.z + p1.z; v.w += p0.w + p1.w;
    *(float4*)&outf[base] = v;

    float s = v.x + v.y + v.z + v.w;
#pragma unroll
    for (int o = 32; o; o >>= 1) s += __shfl_down(s, o);
    if ((tid & 63) == 0) red[tid >> 6] = s;
    __syncthreads();
    float mean = (red[0] + red[1] + red[2] + red[3]) * (1.f / D_DIM);
    __syncthreads();

    float dx = v.x - mean, dy = v.y - mean, dz = v.z - mean, dw = v.w - mean;
    float q = dx * dx + dy * dy + dz * dz + dw * dw;
#pragma unroll
    for (int o = 32; o; o >>= 1) q += __shfl_down(q, o);
    if ((tid & 63) == 0) red[tid >> 6] = q;
    __syncthreads();
    float var = (red[0] + red[1] + red[2] + red[3]) * (1.f / D_DIM);
    float rstd = rsqrtf(var + 1e-5f);

    float4 gv = *(const float4*)&g[tid * 4];
    float4 bv = *(const float4*)&beta[tid * 4];
    bf16_t* op = outn + base;
    op[0] = (bf16_t)(dx * rstd * gv.x + bv.x);
    op[1] = (bf16_t)(dy * rstd * gv.y + bv.y);
    op[2] = (bf16_t)(dz * rstd * gv.z + bv.z);
    op[3] = (bf16_t)(dw * rstd * gv.w + bv.w);
}

// ---------------------------------------------------------------------------
// Fused weighted-sum for Q/K/V: reads y row once, writes sq, sk, sv.
// ---------------------------------------------------------------------------
__global__ __launch_bounds__(256)
void wsf_kernel(const bf16_t* __restrict__ y,
                const float* __restrict__ wfQ, const float* __restrict__ wrQ,
                const float* __restrict__ wfK, const float* __restrict__ wrK,
                const float* __restrict__ wfV, const float* __restrict__ wrV,
                bf16_t* __restrict__ sq, bf16_t* __restrict__ sk, bf16_t* __restrict__ sv)
{
    const int r = threadIdx.x;
    const int row = blockIdx.x;
    const bf16_t* yrow = y + (size_t)row * 4096;
    const float* fQ = wfQ + row * N_NEU;
    const float* fK = wfK + row * N_NEU;
    const float* fV = wfV + row * N_NEU;
    float aQ = 0.f, aK = 0.f, aV = 0.f;
#pragma unroll
    for (int n = 0; n < N_NEU; n++) {
        float yq = (float)yrow[n * R_DIM + r];
        float yv = (float)yrow[2048 + n * R_DIM + r];
        aQ += fQ[n] * yq;
        aK += fK[n] * yq;
        aV += fV[n] * yv;
    }
    const float* rQ = wrQ + row * N_NEU;
    const float* rK = wrK + row * N_NEU;
    const float* rV = wrV + row * N_NEU;
    const size_t rb = (size_t)row * 2048;
#pragma unroll
    for (int n = 0; n < N_NEU; n++) {
        sq[rb + n * R_DIM + r] = (bf16_t)(rQ[n] * aQ);
        sk[rb + n * R_DIM + r] = (bf16_t)(rK[n] * aK);
        sv[rb + n * R_DIM + r] = (bf16_t)(rV[n] * aV);
    }
}

// know-path ws with fused split-K reduce: y = P0+P1 (fp32 partials), KR=128.
__global__ __launch_bounds__(256)
void ws2_kernel(const float* __restrict__ P0, const float* __restrict__ P1,
                const float* __restrict__ wf, const float* __restrict__ wr,
                bf16_t* __restrict__ sout)
{
    const int lr = threadIdx.x >> 7;
    const int r  = threadIdx.x & 127;
    const int row = blockIdx.x * 2 + lr;
    const size_t rb = (size_t)row * (N_NEU * KR_DIM);
    const float* wfp = wf + row * N_NEU;
    const float* wrp = wr + row * N_NEU;
    float acc = 0.f;
#pragma unroll
    for (int n = 0; n < N_NEU; n++) {
        size_t i = rb + n * KR_DIM + r;
        acc += wfp[n] * (P0[i] + P1[i]);
    }
    bf16_t* srow = sout + rb;
#pragma unroll
    for (int n = 0; n < N_NEU; n++) srow[n * KR_DIM + r] = (bf16_t)(wrp[n] * acc);
}

// ---------------------------------------------------------------------------
// GEMM, 2-phase double-buffered (T3 minimum recipe):
//   prologue: STAGE(buf0); barrier
//   loop:     STAGE(buf^1, next) ; ds_read+MFMA(buf) ; barrier ; flip
// C[M,N] = A[M,K] @ Bsel[N,K]^T.  128x128 tile, BK=32.
// EPI=0: bf16 C.  EPI=1: fp32 C = acc + resid.  EPI=2: fp32 partial per
// blockIdx.z (split-K=2).
// ---------------------------------------------------------------------------
template<int EPI>
__global__ __launch_bounds__(256)
void gemm_kernel(const bf16_t* __restrict__ A, const bf16_t* __restrict__ Bt,
                 const bf16_t* __restrict__ Bt2, int splitMy,
                 void* Cout, const float* resid, int M, int N, int K)
{
    __shared__ bf16_t As[2][128][32];
    __shared__ bf16_t Bs[2][128][32];
    const int tid = threadIdx.x;
    const int l = tid & 63, w = tid >> 6;
    const int wr = w >> 1, wc = w & 1;

    // XCD-chunked swizzle (bijective when grid multiple of 8)
    const int nbxy = gridDim.x * gridDim.y;
    int bid = blockIdx.y * gridDim.x + blockIdx.x;
    if ((nbxy & 7) == 0) bid = (bid & 7) * (nbxy >> 3) + (bid >> 3);
    const int bx = bid % gridDim.x, by = bid / gridDim.x;

    const int m0 = by * 128, n0 = bx * 128;
    const bf16_t* Bsel = (by < splitMy) ? Bt : Bt2;

    int kbeg = 0, kend = K;
    if constexpr (EPI == 2) { const int half = K >> 1; kbeg = blockIdx.z * half; kend = kbeg + half; }

    const int srow = l >> 2;
    const int scol = (l & 3) * 8;
    const bf16_t* Ag0 = A    + (size_t)(m0 + w * 32 + srow) * K + scol;
    const bf16_t* Ag1 = Ag0 + (size_t)16 * K;
    const bf16_t* Bg0 = Bsel + (size_t)(n0 + w * 32 + srow) * K + scol;
    const bf16_t* Bg1 = Bg0 + (size_t)16 * K;

    auto stage = [&](int buf, int k0) {
        char* Asb = (char*)&As[buf][0][0] + w * 2048;
        char* Bsb = (char*)&Bs[buf][0][0] + w * 2048;
        gl_lds16(Ag0 + k0, Asb);
        gl_lds16(Ag1 + k0, Asb + 1024);
        gl_lds16(Bg0 + k0, Bsb);
        gl_lds16(Bg1 + k0, Bsb + 1024);
    };

    f32x4 acc[4][4];
    const f32x4 zero = {0.f, 0.f, 0.f, 0.f};
#pragma unroll
    for (int i = 0; i < 4; i++)
#pragma unroll
        for (int j = 0; j < 4; j++) acc[i][j] = zero;

    const int fr = l & 15;
    const int fk = (l >> 4) * 8;

    // prologue
    stage(0, kbeg);
    __syncthreads();

    int cur = 0;
    for (int k0 = kbeg; k0 < kend; k0 += 32) {
        if (k0 + 32 < kend) stage(cur ^ 1, k0 + 32);

        bf16x8 af[4], bv[4];
#pragma unroll
        for (int i = 0; i < 4; i++) af[i] = *(const bf16x8*)&As[cur][wr * 64 + i * 16 + fr][fk];
#pragma unroll
        for (int i = 0; i < 4; i++) bv[i] = *(const bf16x8*)&Bs[cur][wc * 64 + i * 16 + fr][fk];
        __builtin_amdgcn_s_setprio(1);
#pragma unroll
        for (int mi = 0; mi < 4; mi++)
#pragma unroll
            for (int ni = 0; ni < 4; ni++)
                acc[mi][ni] = __builtin_amdgcn_mfma_f32_16x16x32_bf16(af[mi], bv[ni], acc[mi][ni], 0, 0, 0);
        __builtin_amdgcn_s_setprio(0);
        __syncthreads();
        cur ^= 1;
    }

    const int orow = (l >> 4) * 4;
    const int ocol = l & 15;
#pragma unroll
    for (int mi = 0; mi < 4; mi++)
#pragma unroll
        for (int ni = 0; ni < 4; ni++)
#pragma unroll
            for (int j = 0; j < 4; j++) {
                int row = m0 + wr * 64 + mi * 16 + orow + j;
                int col = n0 + wc * 64 + ni * 16 + ocol;
                size_t idx = (size_t)row * N + col;
                if constexpr (EPI == 0) {
                    ((bf16_t*)Cout)[idx] = (bf16_t)acc[mi][ni][j];
                } else if constexpr (EPI == 1) {
                    ((float*)Cout)[idx] = acc[mi][ni][j] + resid[idx];
                } else {
                    ((float*)Cout)[(size_t)blockIdx.z * M * N + idx] = acc[mi][ni][j];
                }
            }
}

// ---------------------------------------------------------------------------
// Causal flash attention (R5 structure + MFMA l-sum).
// Q/K/O: [B*S][1024] bf16 (head h = cols h*64..+64).
// Vt: [B][1024][2048] bf16 (pre-transposed V).
// 1024 blocks.  Balanced XCD-chunked mapping:
//   xcd=bid&7, slot=bid>>3 (0..127), head=slot&3, j=slot>>2,
//   qb = 8u + (u&1 ? 7-t : t), t=j&7, u=j>>3.
// CU c's 4 resident blocks get qb {t,15-t,16+t,31-t} -> exactly 66 tiles/CU.
// l accumulated via la = mfma(P, ones, la): 2 MFMA/tile replace 16 shfl+adds.
// ---------------------------------------------------------------------------
__global__ __launch_bounds__(256)
void fa_kernel(const bf16_t* __restrict__ Q, const bf16_t* __restrict__ K,
               const bf16_t* __restrict__ Vt, bf16_t* __restrict__ O)
{
    __shared__ bf16_t Ks[64][72];
    __shared__ bf16_t Vs[64][72];
    __shared__ bf16_t Ps[4][16][72];

    const int tid = threadIdx.x;
    const int l = tid & 63, w = tid >> 6;

    const int bid = blockIdx.x;
    const int xcd  = bid & 7;
    const int slot = bid >> 3;          // 0..127
    const int head = slot & 3;
    const int j5   = slot >> 2;         // 0..31
    const int t5   = j5 & 7, u5 = j5 >> 3;
    const int qb   = 8 * u5 + ((u5 & 1) ? (7 - t5) : t5);
    const int bh   = xcd * 4 + head;
    const int b = bh >> 4, h = bh & 15;
    const int q0 = qb * 64;

    const bf16_t* Qp = Q + (size_t)b * S_LEN * D_DIM + h * DH;
    const bf16_t* Kp = K + (size_t)b * S_LEN * D_DIM + h * DH;
    const bf16_t* Vp = Vt + (size_t)b * D_DIM * S_LEN + (size_t)h * DH * S_LEN;

    const int fr = l & 15, fg = l >> 4, fk = fg * 8;

    bf16x8 qf[2];
#pragma unroll
    for (int ks = 0; ks < 2; ks++)
        qf[ks] = *(const bf16x8*)(Qp + (size_t)(q0 + w * 16 + fr) * D_DIM + ks * 32 + fk);

    bf16x8 ones8;
#pragma unroll
    for (int i = 0; i < 8; i++) ones8[i] = (bf16_t)1.f;

    const f32x4 zero = {0.f, 0.f, 0.f, 0.f};
    f32x4 o[4];
    f32x4 la = zero;                  // row sums (all cols equal)
    float m_r[4];
#pragma unroll
    for (int j = 0; j < 4; j++) { o[j] = zero; m_r[j] = -1e30f; }

    const int srow = tid >> 2;
    const int scol = (tid & 3) * 16;
    const bf16_t* Kst = Kp + (size_t)srow * D_DIM + scol;
    const bf16_t* Vst = Vp + (size_t)srow * S_LEN + scol;

    const int nt = q0 / 64 + 1;
    const float C_LOG2 = 0.125f * 1.44269504f;   // 1/sqrt(DH) * log2(e)

    // prologue: issue loads for tile 0
    uint4 kva = *(const uint4*)(Kst);
    uint4 kvb = *(const uint4*)(Kst + 8);
    uint4 vva = *(const uint4*)(Vst);
    uint4 vvb = *(const uint4*)(Vst + 8);

    for (int t = 0; t < nt; t++) {
        const int k0 = t * 64;
        __syncthreads();              // previous tile's reads complete
        *(uint4*)&Ks[srow][scol]     = kva;
        *(uint4*)&Ks[srow][scol + 8] = kvb;
        *(uint4*)&Vs[srow][scol]     = vva;
        *(uint4*)&Vs[srow][scol + 8] = vvb;
        __syncthreads();

        if (t + 1 < nt) {             // T14: issue next tile's loads now
            const int kn = k0 + 64;
            kva = *(const uint4*)(Kst + (size_t)kn * D_DIM);
            kvb = *(const uint4*)(Kst + (size_t)kn * D_DIM + 8);
            vva = *(const uint4*)(Vst + kn);
            vvb = *(const uint4*)(Vst + kn + 8);
        }

        // ---- QK^T: 16 q-rows x 64 keys ----
        f32x4 sc[4];
#pragma unroll
        for (int ni = 0; ni < 4; ni++) sc[ni] = zero;
        __builtin_amdgcn_s_setprio(1);
#pragma unroll
        for (int ks = 0; ks < 2; ks++) {
#pragma unroll
            for (int ni = 0; ni < 4; ni++) {
                bf16x8 kf = *(const bf16x8*)&Ks[ni * 16 + fr][ks * 32 + fk];
                sc[ni] = __builtin_amdgcn_mfma_f32_16x16x32_bf16(qf[ks], kf, sc[ni], 0, 0, 0);
            }
        }
        __builtin_amdgcn_s_setprio(0);

        // ---- scale to log2 domain + causal mask ----
        float p[4][4];
#pragma unroll
        for (int ni = 0; ni < 4; ni++) {
            const int key = k0 + ni * 16 + fr;
#pragma unroll
            for (int j = 0; j < 4; j++) {
                const int qg = q0 + w * 16 + fg * 4 + j;
                p[ni][j] = (key <= qg) ? sc[ni][j] * C_LOG2 : -1e30f;
            }
        }

        // ---- online softmax (exp2 domain), defer-max (T13); no sum-reduce ----
#pragma unroll
        for (int j = 0; j < 4; j++) {
            float rmax = fmaxf(fmaxf(p[0][j], p[1][j]), fmaxf(p[2][j], p[3][j]));
#pragma unroll
            for (int d = 1; d < 16; d <<= 1) rmax = fmaxf(rmax, __shfl_xor(rmax, d));
            if (rmax > m_r[j] + 8.f) {         // rescale only on real growth
                float scale = exp2f(m_r[j] - rmax);
                la[j] *= scale;
#pragma unroll
                for (int nc = 0; nc < 4; nc++) o[nc][j] *= scale;
                m_r[j] = rmax;
            }
#pragma unroll
            for (int ni = 0; ni < 4; ni++)
                p[ni][j] = exp2f(p[ni][j] - m_r[j]);   // bounded by 2^8
        }

        // ---- P -> A-layout via per-wave LDS bounce ----
#pragma unroll
        for (int ni = 0; ni < 4; ni++)
#pragma unroll
            for (int j = 0; j < 4; j++)
                Ps[w][fg * 4 + j][ni * 16 + fr] = (bf16_t)p[ni][j];

        // ---- PV + l-sum (la rides the MFMA pipe) ----
        __builtin_amdgcn_s_setprio(1);
#pragma unroll
        for (int ks = 0; ks < 2; ks++) {
            bf16x8 pa = *(const bf16x8*)&Ps[w][fr][ks * 32 + fk];
            la = __builtin_amdgcn_mfma_f32_16x16x32_bf16(pa, ones8, la, 0, 0, 0);
#pragma unroll
            for (int nc = 0; nc < 4; nc++) {
                bf16x8 vf = *(const bf16x8*)&Vs[nc * 16 + fr][ks * 32 + fk];
                o[nc] = __builtin_amdgcn_mfma_f32_16x16x32_bf16(pa, vf, o[nc], 0, 0, 0);
            }
        }
        __builtin_amdgcn_s_setprio(0);
    }

    // ---- epilogue ----
#pragma unroll
    for (int j = 0; j < 4; j++) {
        const float inv = 1.f / la[j];
        const int q = q0 + w * 16 + fg * 4 + j;
        bf16_t* op = O + (size_t)(b * S_LEN + q) * D_DIM + h * DH;
#pragma unroll
        for (int nc = 0; nc < 4; nc++)
            op[nc * 16 + fr] = (bf16_t)(o[nc][j] * inv);
    }
}

// ---------------------------------------------------------------------------
extern "C" void kernel_launch(void* const* d_in, const int* in_sizes, int n_in,
                              void* d_out, int out_size, void* d_ws, size_t ws_size,
                              hipStream_t stream)
{
    const float* x      = (const float*)d_in[0];
    const float* fqk_wQ = (const float*)d_in[1];
    const float* fqk_wK = (const float*)d_in[2];
    const float* fv_w   = (const float*)d_in[3];
    const float* rqk_wQ = (const float*)d_in[4];
    const float* rqk_wK = (const float*)d_in[5];
    const float* rv_w   = (const float*)d_in[6];
    const float* fkn_w  = (const float*)d_in[7];
    const float* rkn_w  = (const float*)d_in[8];
    const float* f_qk   = (const float*)d_in[9];
    const float* f_v    = (const float*)d_in[10];
    const float* r_qk   = (const float*)d_in[11];
    const float* r_v    = (const float*)d_in[12];
    const float* f_know = (const float*)d_in[13];
    const float* r_know = (const float*)d_in[14];
    const float* W_O    = (const float*)d_in[15];
    const float* ln1g   = (const float*)d_in[16];
    const float* ln1b   = (const float*)d_in[17];
    const float* ln2g   = (const float*)d_in[18];
    const float* ln2b   = (const float*)d_in[19];
    float* out_f = (float*)d_out;
    (void)ws_size; (void)in_sizes; (void)n_in; (void)out_size;

    // ---- workspace layout (reused slots) ----
    char* ws = (char*)d_ws;
    const size_t MB = 1024 * 1024;
    bf16_t* rqkT   = (bf16_t*)(ws + 0 * MB);    // [1024][2048]  4MB
    bf16_t* rvT    = (bf16_t*)(ws + 4 * MB);    // [1024][2048]  4MB
    bf16_t* rknT   = (bf16_t*)(ws + 8 * MB);    // [1024][1024]  2MB
    bf16_t* woB    = (bf16_t*)(ws + 10 * MB);   // [1024][1024]  2MB
    bf16_t* fknT   = (bf16_t*)(ws + 12 * MB);   // [1024][1024]  2MB
    bf16_t* buf_nx = (bf16_t*)(ws + 14 * MB);   // 8MB: nx -> Vt -> nx2
    bf16_t* buf_y  = (bf16_t*)(ws + 22 * MB);   // 32MB: y[4096][4096] -> QKV[12288][1024]
    char*   buf_s  = ws + 54 * MB;              // 48MB
    bf16_t* fqkT   = (bf16_t*)(buf_s);               // [2048][1024] 4MB (pre-ws only)
    bf16_t* fvT    = (bf16_t*)(buf_s + 4 * MB);      // contiguous -> N=4096 B
    bf16_t* s_q    = (bf16_t*)(buf_s);               // [12288][2048] grouped A
    bf16_t* s_k    = (bf16_t*)(buf_s) + (size_t)4096 * 2048;
    bf16_t* s_v    = (bf16_t*)(buf_s) + (size_t)8192 * 2048;
    bf16_t* attn   = (bf16_t*)(buf_s);               // [4096][1024] 8MB
    float*  P0     = (float*)(buf_s + 16 * MB);      // W_O split-K partials 2x16MB
    float*  P0k    = (float*)(buf_s);                // know split-K partials
    float*  P1k    = (float*)(buf_s + 16 * MB);
    bf16_t* sk2    = (bf16_t*)(buf_s + 32 * MB);     // [4096][1024] 8MB
    bf16_t* Qb     = buf_y;                          // QKV contiguous [12288][1024]
    bf16_t* Kb     = buf_y + (size_t)4096 * 1024;
    bf16_t* Vb     = buf_y + (size_t)8192 * 1024;
    bf16_t* Vt     = buf_nx;                         // [2][1024][2048]

    const dim3 blk256(256), blkT(32, 8);

    // ---- weight conversion ----
    tcast_kernel<<<dim3(R_DIM / 32, D_DIM / 32, N_NEU), blkT, 0, stream>>>(f_qk, fqkT, D_DIM, R_DIM);
    tcast_kernel<<<dim3(R_DIM / 32, D_DIM / 32, N_NEU), blkT, 0, stream>>>(f_v, fvT, D_DIM, R_DIM);
    tcast_kernel<<<dim3(KR_DIM / 32, D_DIM / 32, N_NEU), blkT, 0, stream>>>(f_know, fknT, D_DIM, KR_DIM);
    tcast_kernel<<<dim3(D_DIM / 32, 2048 / 32, 1), blkT, 0, stream>>>(r_qk, rqkT, 2048, D_DIM);
    tcast_kernel<<<dim3(D_DIM / 32, 2048 / 32, 1), blkT, 0, stream>>>(r_v, rvT, 2048, D_DIM);
    tcast_kernel<<<dim3(D_DIM / 32, 1024 / 32, 1), blkT, 0, stream>>>(r_know, rknT, 1024, D_DIM);
    cast_kernel<<<dim3(1024 * 1024 / 4 / 256), blk256, 0, stream>>>(W_O, woB, 1024 * 1024 / 4);

    // ---- LN1 ----
    ln_kernel<<<dim3(ROWS), blk256, 0, stream>>>(x, ln1g, ln1b, buf_nx);

    // ---- fused feature GEMM: y[4096][4096] = nx @ [fqkT;fvT]^T ----
    gemm_kernel<0><<<dim3(32, 32), blk256, 0, stream>>>(buf_nx, fqkT, fqkT, 1 << 30, buf_y, nullptr, 4096, 4096, 1024);

    // ---- fused weighted sums -> sq|sk|sv [12288][2048] ----
    wsf_kernel<<<dim3(ROWS), blk256, 0, stream>>>(buf_y, fqk_wQ, rqk_wQ, fqk_wK, rqk_wK, fv_w, rv_w, s_q, s_k, s_v);

    // ---- grouped restore GEMM: QKV[12288][1024] (768 blocks, B-select) ----
    gemm_kernel<0><<<dim3(8, 96), blk256, 0, stream>>>((bf16_t*)buf_s, rqkT, rvT, 64, buf_y, nullptr, 12288, 1024, 2048);

    // ---- V -> Vt ----
    tbf_kernel<<<dim3(D_DIM / 32, S_LEN / 32, B_DIM), blkT, 0, stream>>>(Vb, Vt, S_LEN, D_DIM);

    // ---- attention (1024 blocks, balanced mapping) ----
    fa_kernel<<<dim3(1024), blk256, 0, stream>>>(Qb, Kb, Vt, attn);

    // ---- W_O split-K=2: partials P0/P1 (512 blocks) ----
    gemm_kernel<2><<<dim3(8, 32, 2), blk256, 0, stream>>>(attn, woB, woB, 1 << 30, P0, nullptr, 4096, 1024, 1024);

    // ---- LN2 fused: d_out = x + P0 + P1; nx2 = LN(d_out) ----
    ln2x_kernel<<<dim3(ROWS), blk256, 0, stream>>>(x, P0, P0 + (size_t)4096 * 1024, ln2g, ln2b, out_f, buf_nx);

    // ---- know feature split-K=2: partials P0k/P1k (512 blocks) ----
    gemm_kernel<2><<<dim3(8, 32, 2), blk256, 0, stream>>>(buf_nx, fknT, fknT, 1 << 30, P0k, nullptr, 4096, 1024, 1024);

    // ---- know ws (fused reduce) -> sk2 ----
    ws2_kernel<<<dim3(ROWS / 2), blk256, 0, stream>>>(P0k, P1k, fkn_w, rkn_w, sk2);

    // ---- out = sk2 @ rknT^T + x2 -> d_out ----
    gemm_kernel<1><<<dim3(8, 32), blk256, 0, stream>>>(sk2, rknT, rknT, 1 << 30, d_out, out_f, 4096, 1024, 1024);
}

// Round 8
// 317.851 us; speedup vs baseline: 1.1373x; 1.0395x over previous
//
#include <hip/hip_runtime.h>
#include <hip/hip_bf16.h>

// ---------------------------------------------------------------------------
// DAWN block on MI355X.  Round 8:
//  - GEMM: 3-buffer pipeline with counted vmcnt(4) + raw s_barrier (T4) —
//    staging latency gets ~2 iterations of MFMA cover instead of <1.
//  - fa: two-pass balanced blocks (512 blocks x exactly 33 tiles each),
//    causal-mask VALU only on the diagonal tile.
// ---------------------------------------------------------------------------

typedef __bf16 bf16_t;
typedef __bf16 bf16x8 __attribute__((ext_vector_type(8)));
typedef float f32x4 __attribute__((ext_vector_type(4)));

#define B_DIM 2
#define S_LEN 2048
#define D_DIM 1024
#define H_NUM 16
#define DH 64
#define N_NEU 8
#define R_DIM 256
#define KR_DIM 128
#define ROWS (B_DIM * S_LEN)   // 4096

static __device__ __forceinline__ void gl_lds16(const void* g, void* l)
{
    __builtin_amdgcn_global_load_lds(
        (__attribute__((address_space(1))) void*)(g),
        (__attribute__((address_space(3))) void*)(l), 16, 0, 0);
}

// ---------------------------------------------------------------------------
// Batched transpose-cast: in[z][I][J] f32 -> out[z][J][I] bf16.  block (32,8)
// ---------------------------------------------------------------------------
__global__ __launch_bounds__(256)
void tcast_kernel(const float* __restrict__ in, bf16_t* __restrict__ out, int I, int J)
{
    __shared__ float t[32][33];
    const int bJ = blockIdx.x * 32, bI = blockIdx.y * 32;
    const size_t boff = (size_t)blockIdx.z * I * J;
    const int tx = threadIdx.x, ty = threadIdx.y;
#pragma unroll
    for (int i = 0; i < 4; i++)
        t[ty * 4 + i][tx] = in[boff + (size_t)(bI + ty * 4 + i) * J + bJ + tx];
    __syncthreads();
#pragma unroll
    for (int i = 0; i < 4; i++)
        out[boff + (size_t)(bJ + ty * 4 + i) * I + bI + tx] = (bf16_t)t[tx][ty * 4 + i];
}

// bf16 transpose: in[z][I][J] -> out[z][J][I].  block (32,8)
__global__ __launch_bounds__(256)
void tbf_kernel(const bf16_t* __restrict__ in, bf16_t* __restrict__ out, int I, int J)
{
    __shared__ bf16_t t[32][33];
    const int bJ = blockIdx.x * 32, bI = blockIdx.y * 32;
    const size_t boff = (size_t)blockIdx.z * I * J;
    const int tx = threadIdx.x, ty = threadIdx.y;
#pragma unroll
    for (int i = 0; i < 4; i++)
        t[ty * 4 + i][tx] = in[boff + (size_t)(bI + ty * 4 + i) * J + bJ + tx];
    __syncthreads();
#pragma unroll
    for (int i = 0; i < 4; i++)
        out[boff + (size_t)(bJ + ty * 4 + i) * I + bI + tx] = t[tx][ty * 4 + i];
}

// plain cast fp32 -> bf16 (vectorized by 4)
__global__ __launch_bounds__(256)
void cast_kernel(const float* __restrict__ in, bf16_t* __restrict__ out, int n4)
{
    int i = blockIdx.x * 256 + threadIdx.x;
    if (i < n4) {
        float4 v = ((const float4*)in)[i];
        bf16_t* op = out + (size_t)i * 4;
        op[0] = (bf16_t)v.x; op[1] = (bf16_t)v.y; op[2] = (bf16_t)v.z; op[3] = (bf16_t)v.w;
    }
}

// ---------------------------------------------------------------------------
// LayerNorm over D=1024, one row per block. fp32 in, bf16 out.
// ---------------------------------------------------------------------------
__global__ __launch_bounds__(256)
void ln_kernel(const float* __restrict__ x, const float* __restrict__ g,
               const float* __restrict__ beta, bf16_t* __restrict__ out)
{
    __shared__ float red[4];
    const int row = blockIdx.x;
    const int tid = threadIdx.x;
    float4 v = *(const float4*)&x[(size_t)row * D_DIM + tid * 4];

    float s = v.x + v.y + v.z + v.w;
#pragma unroll
    for (int o = 32; o; o >>= 1) s += __shfl_down(s, o);
    if ((tid & 63) == 0) red[tid >> 6] = s;
    __syncthreads();
    float mean = (red[0] + red[1] + red[2] + red[3]) * (1.f / D_DIM);
    __syncthreads();

    float dx = v.x - mean, dy = v.y - mean, dz = v.z - mean, dw = v.w - mean;
    float q = dx * dx + dy * dy + dz * dz + dw * dw;
#pragma unroll
    for (int o = 32; o; o >>= 1) q += __shfl_down(q, o);
    if ((tid & 63) == 0) red[tid >> 6] = q;
    __syncthreads();
    float var = (red[0] + red[1] + red[2] + red[3]) * (1.f / D_DIM);
    float rstd = rsqrtf(var + 1e-5f);

    float4 gv = *(const float4*)&g[tid * 4];
    float4 bv = *(const float4*)&beta[tid * 4];
    bf16_t* op = out + (size_t)row * D_DIM + tid * 4;
    op[0] = (bf16_t)(dx * rstd * gv.x + bv.x);
    op[1] = (bf16_t)(dy * rstd * gv.y + bv.y);
    op[2] = (bf16_t)(dz * rstd * gv.z + bv.z);
    op[3] = (bf16_t)(dw * rstd * gv.w + bv.w);
}

// ---------------------------------------------------------------------------
// LN2 with fused split-K reduce + residual:  sum = x + P0 + P1 -> outf (fp32),
// then LN(sum) -> bf16 outn.
// ---------------------------------------------------------------------------
__global__ __launch_bounds__(256)
void ln2x_kernel(const float* __restrict__ x, const float* __restrict__ P0,
                 const float* __restrict__ P1, const float* __restrict__ g,
                 const float* __restrict__ beta, float* __restrict__ outf,
                 bf16_t* __restrict__ outn)
{
    __shared__ float red[4];
    const int row = blockIdx.x;
    const int tid = threadIdx.x;
    const size_t base = (size_t)row * D_DIM + tid * 4;
    float4 v  = *(const float4*)&x[base];
    float4 p0 = *(const float4*)&P0[base];
    float4 p1 = *(const float4*)&P1[base];
    v.x += p0.x + p1.x; v.y += p0.y + p1.y; v.z += p0.z + p1.z; v.w += p0.w + p1.w;
    *(float4*)&outf[base] = v;

    float s = v.x + v.y + v.z + v.w;
#pragma unroll
    for (int o = 32; o; o >>= 1) s += __shfl_down(s, o);
    if ((tid & 63) == 0) red[tid >> 6] = s;
    __syncthreads();
    float mean = (red[0] + red[1] + red[2] + red[3]) * (1.f / D_DIM);
    __syncthreads();

    float dx = v.x - mean, dy = v.y - mean, dz = v.z - mean, dw = v.w - mean;
    float q = dx * dx + dy * dy + dz * dz + dw * dw;
#pragma unroll
    for (int o = 32; o; o >>= 1) q += __shfl_down(q, o);
    if ((tid & 63) == 0) red[tid >> 6] = q;
    __syncthreads();
    float var = (red[0] + red[1] + red[2] + red[3]) * (1.f / D_DIM);
    float rstd = rsqrtf(var + 1e-5f);

    float4 gv = *(const float4*)&g[tid * 4];
    float4 bv = *(const float4*)&beta[tid * 4];
    bf16_t* op = outn + base;
    op[0] = (bf16_t)(dx * rstd * gv.x + bv.x);
    op[1] = (bf16_t)(dy * rstd * gv.y + bv.y);
    op[2] = (bf16_t)(dz * rstd * gv.z + bv.z);
    op[3] = (bf16_t)(dw * rstd * gv.w + bv.w);
}

// ---------------------------------------------------------------------------
// Fused weighted-sum for Q/K/V: reads y row once, writes sq, sk, sv.
// ---------------------------------------------------------------------------
__global__ __launch_bounds__(256)
void wsf_kernel(const bf16_t* __restrict__ y,
                const float* __restrict__ wfQ, const float* __restrict__ wrQ,
                const float* __restrict__ wfK, const float* __restrict__ wrK,
                const float* __restrict__ wfV, const float* __restrict__ wrV,
                bf16_t* __restrict__ sq, bf16_t* __restrict__ sk, bf16_t* __restrict__ sv)
{
    const int r = threadIdx.x;
    const int row = blockIdx.x;
    const bf16_t* yrow = y + (size_t)row * 4096;
    const float* fQ = wfQ + row * N_NEU;
    const float* fK = wfK + row * N_NEU;
    const float* fV = wfV + row * N_NEU;
    float aQ = 0.f, aK = 0.f, aV = 0.f;
#pragma unroll
    for (int n = 0; n < N_NEU; n++) {
        float yq = (float)yrow[n * R_DIM + r];
        float yv = (float)yrow[2048 + n * R_DIM + r];
        aQ += fQ[n] * yq;
        aK += fK[n] * yq;
        aV += fV[n] * yv;
    }
    const float* rQ = wrQ + row * N_NEU;
    const float* rK = wrK + row * N_NEU;
    const float* rV = wrV + row * N_NEU;
    const size_t rb = (size_t)row * 2048;
#pragma unroll
    for (int n = 0; n < N_NEU; n++) {
        sq[rb + n * R_DIM + r] = (bf16_t)(rQ[n] * aQ);
        sk[rb + n * R_DIM + r] = (bf16_t)(rK[n] * aK);
        sv[rb + n * R_DIM + r] = (bf16_t)(rV[n] * aV);
    }
}

// know-path ws with fused split-K reduce: y = P0+P1 (fp32 partials), KR=128.
__global__ __launch_bounds__(256)
void ws2_kernel(const float* __restrict__ P0, const float* __restrict__ P1,
                const float* __restrict__ wf, const float* __restrict__ wr,
                bf16_t* __restrict__ sout)
{
    const int lr = threadIdx.x >> 7;
    const int r  = threadIdx.x & 127;
    const int row = blockIdx.x * 2 + lr;
    const size_t rb = (size_t)row * (N_NEU * KR_DIM);
    const float* wfp = wf + row * N_NEU;
    const float* wrp = wr + row * N_NEU;
    float acc = 0.f;
#pragma unroll
    for (int n = 0; n < N_NEU; n++) {
        size_t i = rb + n * KR_DIM + r;
        acc += wfp[n] * (P0[i] + P1[i]);
    }
    bf16_t* srow = sout + rb;
#pragma unroll
    for (int n = 0; n < N_NEU; n++) srow[n * KR_DIM + r] = (bf16_t)(wrp[n] * acc);
}

// ---------------------------------------------------------------------------
// GEMM, 3-buffer pipeline with counted vmcnt (T3+T4):
//   prologue: STAGE(buf0,t0); STAGE(buf1,t1)
//   iter k:   vmcnt(4) [vmcnt(0) on last]; s_barrier; ds_read(buf k%3);
//             STAGE(buf (k+2)%3, t k+2); MFMA
// Per-wave outstanding loads = 8 steady-state; vmcnt(4) => tile k landed.
// Buffer overwritten at distance 3: all waves crossed a barrier after their
// reads completed (lgkmcnt before MFMA precedes the barrier) -> race-free.
// C[M,N] = A[M,K] @ Bsel[N,K]^T.  128x128 tile, BK=32.
// EPI=0: bf16 C.  EPI=1: fp32 C = acc + resid.  EPI=2: fp32 partial per
// blockIdx.z (split-K=2).
// ---------------------------------------------------------------------------
template<int EPI>
__global__ __launch_bounds__(256)
void gemm_kernel(const bf16_t* __restrict__ A, const bf16_t* __restrict__ Bt,
                 const bf16_t* __restrict__ Bt2, int splitMy,
                 void* Cout, const float* resid, int M, int N, int K)
{
    __shared__ bf16_t As[3][128][32];
    __shared__ bf16_t Bs[3][128][32];
    const int tid = threadIdx.x;
    const int l = tid & 63, w = tid >> 6;
    const int wr = w >> 1, wc = w & 1;

    // XCD-chunked swizzle (bijective when grid multiple of 8)
    const int nbxy = gridDim.x * gridDim.y;
    int bid = blockIdx.y * gridDim.x + blockIdx.x;
    if ((nbxy & 7) == 0) bid = (bid & 7) * (nbxy >> 3) + (bid >> 3);
    const int bx = bid % gridDim.x, by = bid / gridDim.x;

    const int m0 = by * 128, n0 = bx * 128;
    const bf16_t* Bsel = (by < splitMy) ? Bt : Bt2;

    int kbeg = 0, kend = K;
    if constexpr (EPI == 2) { const int half = K >> 1; kbeg = blockIdx.z * half; kend = kbeg + half; }

    const int srow = l >> 2;
    const int scol = (l & 3) * 8;
    const bf16_t* Ag0 = A    + (size_t)(m0 + w * 32 + srow) * K + scol;
    const bf16_t* Ag1 = Ag0 + (size_t)16 * K;
    const bf16_t* Bg0 = Bsel + (size_t)(n0 + w * 32 + srow) * K + scol;
    const bf16_t* Bg1 = Bg0 + (size_t)16 * K;

    auto stage = [&](int buf, int k0) {
        char* Asb = (char*)&As[buf][0][0] + w * 2048;
        char* Bsb = (char*)&Bs[buf][0][0] + w * 2048;
        gl_lds16(Ag0 + k0, Asb);
        gl_lds16(Ag1 + k0, Asb + 1024);
        gl_lds16(Bg0 + k0, Bsb);
        gl_lds16(Bg1 + k0, Bsb + 1024);
    };

    f32x4 acc[4][4];
    const f32x4 zero = {0.f, 0.f, 0.f, 0.f};
#pragma unroll
    for (int i = 0; i < 4; i++)
#pragma unroll
        for (int j = 0; j < 4; j++) acc[i][j] = zero;

    const int fr = l & 15;
    const int fk = (l >> 4) * 8;

    // prologue: stage tiles 0 and 1 (all our K >= 512, nK >= 16)
    stage(0, kbeg);
    stage(1, kbeg + 32);

    const int nK = (kend - kbeg) >> 5;
    for (int it = 0; it < nK; ++it) {
        if (it + 1 < nK) {
            asm volatile("s_waitcnt vmcnt(4)" ::: "memory");
        } else {
            asm volatile("s_waitcnt vmcnt(0)" ::: "memory");
        }
        __builtin_amdgcn_s_barrier();
        __builtin_amdgcn_sched_barrier(0);   // pin: nothing crosses the barrier

        const int cur = it % 3;
        bf16x8 af[4], bv[4];
#pragma unroll
        for (int i = 0; i < 4; i++) af[i] = *(const bf16x8*)&As[cur][wr * 64 + i * 16 + fr][fk];
#pragma unroll
        for (int i = 0; i < 4; i++) bv[i] = *(const bf16x8*)&Bs[cur][wc * 64 + i * 16 + fr][fk];

        if (it + 2 < nK) stage((it + 2) % 3, kbeg + (it + 2) * 32);

        __builtin_amdgcn_s_setprio(1);
#pragma unroll
        for (int mi = 0; mi < 4; mi++)
#pragma unroll
            for (int ni = 0; ni < 4; ni++)
                acc[mi][ni] = __builtin_amdgcn_mfma_f32_16x16x32_bf16(af[mi], bv[ni], acc[mi][ni], 0, 0, 0);
        __builtin_amdgcn_s_setprio(0);
    }

    const int orow = (l >> 4) * 4;
    const int ocol = l & 15;
#pragma unroll
    for (int mi = 0; mi < 4; mi++)
#pragma unroll
        for (int ni = 0; ni < 4; ni++)
#pragma unroll
            for (int j = 0; j < 4; j++) {
                int row = m0 + wr * 64 + mi * 16 + orow + j;
                int col = n0 + wc * 64 + ni * 16 + ocol;
                size_t idx = (size_t)row * N + col;
                if constexpr (EPI == 0) {
                    ((bf16_t*)Cout)[idx] = (bf16_t)acc[mi][ni][j];
                } else if constexpr (EPI == 1) {
                    ((float*)Cout)[idx] = acc[mi][ni][j] + resid[idx];
                } else {
                    ((float*)Cout)[(size_t)blockIdx.z * M * N + idx] = acc[mi][ni][j];
                }
            }
}

// ---------------------------------------------------------------------------
// Causal flash attention, two-pass balanced blocks.
// Q/K/O: [B*S][1024] bf16 (head h = cols h*64..+64).
// Vt: [B][1024][2048] bf16 (pre-transposed V).
// 512 blocks: xcd=bid&7, slot=bid>>3 (0..63), head=slot&3, j=slot>>2 (0..15).
// Block processes q-tiles (31-j) then (j): exactly (32-j)+(j+1)=33 tiles —
// every block identical length, every CU identical span, same head per CU.
// KVBLK=64, T14 issue-early staging, exp2 softmax, defer-max (T13),
// MFMA l-sum, mask only on diagonal tile.
// ---------------------------------------------------------------------------
__global__ __launch_bounds__(256)
void fa_kernel(const bf16_t* __restrict__ Q, const bf16_t* __restrict__ K,
               const bf16_t* __restrict__ Vt, bf16_t* __restrict__ O)
{
    __shared__ bf16_t Ks[64][72];
    __shared__ bf16_t Vs[64][72];
    __shared__ bf16_t Ps[4][16][72];

    const int tid = threadIdx.x;
    const int l = tid & 63, w = tid >> 6;

    const int bid  = blockIdx.x;
    const int xcd  = bid & 7;
    const int slot = bid >> 3;          // 0..63
    const int head = slot & 3;
    const int jq   = slot >> 2;         // 0..15
    const int bh   = xcd * 4 + head;
    const int b = bh >> 4, h = bh & 15;

    const bf16_t* Qp = Q + (size_t)b * S_LEN * D_DIM + h * DH;
    const bf16_t* Kp = K + (size_t)b * S_LEN * D_DIM + h * DH;
    const bf16_t* Vp = Vt + (size_t)b * D_DIM * S_LEN + (size_t)h * DH * S_LEN;

    const int fr = l & 15, fg = l >> 4, fk = fg * 8;
    const int srow = tid >> 2;
    const int scol = (tid & 3) * 16;
    const bf16_t* Kst = Kp + (size_t)srow * D_DIM + scol;
    const bf16_t* Vst = Vp + (size_t)srow * S_LEN + scol;

    bf16x8 ones8;
#pragma unroll
    for (int i = 0; i < 8; i++) ones8[i] = (bf16_t)1.f;

    const f32x4 zero = {0.f, 0.f, 0.f, 0.f};
    const float C_LOG2 = 0.125f * 1.44269504f;   // 1/sqrt(DH) * log2(e)

    for (int pass = 0; pass < 2; ++pass) {
        const int qb = pass ? jq : (31 - jq);    // long pass first
        const int q0 = qb * 64;
        const int nt = qb + 1;

        bf16x8 qf[2];
#pragma unroll
        for (int ks = 0; ks < 2; ks++)
            qf[ks] = *(const bf16x8*)(Qp + (size_t)(q0 + w * 16 + fr) * D_DIM + ks * 32 + fk);

        f32x4 o[4];
        f32x4 la = zero;
        float m_r[4];
#pragma unroll
        for (int j = 0; j < 4; j++) { o[j] = zero; m_r[j] = -1e30f; }

        // prologue: issue loads for tile 0
        uint4 kva = *(const uint4*)(Kst);
        uint4 kvb = *(const uint4*)(Kst + 8);
        uint4 vva = *(const uint4*)(Vst);
        uint4 vvb = *(const uint4*)(Vst + 8);

        for (int t = 0; t < nt; t++) {
            const int k0 = t * 64;
            __syncthreads();              // previous tile's reads complete
            *(uint4*)&Ks[srow][scol]     = kva;
            *(uint4*)&Ks[srow][scol + 8] = kvb;
            *(uint4*)&Vs[srow][scol]     = vva;
            *(uint4*)&Vs[srow][scol + 8] = vvb;
            __syncthreads();

            if (t + 1 < nt) {             // T14: issue next tile's loads now
                const int kn = k0 + 64;
                kva = *(const uint4*)(Kst + (size_t)kn * D_DIM);
                kvb = *(const uint4*)(Kst + (size_t)kn * D_DIM + 8);
                vva = *(const uint4*)(Vst + kn);
                vvb = *(const uint4*)(Vst + kn + 8);
            }

            // ---- QK^T: 16 q-rows x 64 keys ----
            f32x4 sc[4];
#pragma unroll
            for (int ni = 0; ni < 4; ni++) sc[ni] = zero;
            __builtin_amdgcn_s_setprio(1);
#pragma unroll
            for (int ks = 0; ks < 2; ks++) {
#pragma unroll
                for (int ni = 0; ni < 4; ni++) {
                    bf16x8 kf = *(const bf16x8*)&Ks[ni * 16 + fr][ks * 32 + fk];
                    sc[ni] = __builtin_amdgcn_mfma_f32_16x16x32_bf16(qf[ks], kf, sc[ni], 0, 0, 0);
                }
            }
            __builtin_amdgcn_s_setprio(0);

            // ---- scale to log2 domain (+ causal mask on diagonal tile only) ----
            float p[4][4];
            if (t == qb) {
#pragma unroll
                for (int ni = 0; ni < 4; ni++) {
                    const int key = k0 + ni * 16 + fr;
#pragma unroll
                    for (int j = 0; j < 4; j++) {
                        const int qg = q0 + w * 16 + fg * 4 + j;
                        p[ni][j] = (key <= qg) ? sc[ni][j] * C_LOG2 : -1e30f;
                    }
                }
            } else {
#pragma unroll
                for (int ni = 0; ni < 4; ni++)
#pragma unroll
                    for (int j = 0; j < 4; j++)
                        p[ni][j] = sc[ni][j] * C_LOG2;
            }

            // ---- online softmax (exp2 domain), defer-max (T13) ----
#pragma unroll
            for (int j = 0; j < 4; j++) {
                float rmax = fmaxf(fmaxf(p[0][j], p[1][j]), fmaxf(p[2][j], p[3][j]));
#pragma unroll
                for (int d = 1; d < 16; d <<= 1) rmax = fmaxf(rmax, __shfl_xor(rmax, d));
                if (rmax > m_r[j] + 8.f) {         // rescale only on real growth
                    float scale = exp2f(m_r[j] - rmax);
                    la[j] *= scale;
#pragma unroll
                    for (int nc = 0; nc < 4; nc++) o[nc][j] *= scale;
                    m_r[j] = rmax;
                }
#pragma unroll
                for (int ni = 0; ni < 4; ni++)
                    p[ni][j] = exp2f(p[ni][j] - m_r[j]);   // bounded by 2^8
            }

            // ---- P -> A-layout via per-wave LDS bounce ----
#pragma unroll
            for (int ni = 0; ni < 4; ni++)
#pragma unroll
                for (int j = 0; j < 4; j++)
                    Ps[w][fg * 4 + j][ni * 16 + fr] = (bf16_t)p[ni][j];

            // ---- PV + l-sum (la rides the MFMA pipe) ----
            __builtin_amdgcn_s_setprio(1);
#pragma unroll
            for (int ks = 0; ks < 2; ks++) {
                bf16x8 pa = *(const bf16x8*)&Ps[w][fr][ks * 32 + fk];
                la = __builtin_amdgcn_mfma_f32_16x16x32_bf16(pa, ones8, la, 0, 0, 0);
#pragma unroll
                for (int nc = 0; nc < 4; nc++) {
                    bf16x8 vf = *(const bf16x8*)&Vs[nc * 16 + fr][fk + ks * 32];
                    o[nc] = __builtin_amdgcn_mfma_f32_16x16x32_bf16(pa, vf, o[nc], 0, 0, 0);
                }
            }
            __builtin_amdgcn_s_setprio(0);
        }

        // ---- epilogue for this q-tile ----
#pragma unroll
        for (int j = 0; j < 4; j++) {
            const float inv = 1.f / la[j];
            const int q = q0 + w * 16 + fg * 4 + j;
            bf16_t* op = O + (size_t)(b * S_LEN + q) * D_DIM + h * DH;
#pragma unroll
            for (int nc = 0; nc < 4; nc++)
                op[nc * 16 + fr] = (bf16_t)(o[nc][j] * inv);
        }
    }
}

// ---------------------------------------------------------------------------
extern "C" void kernel_launch(void* const* d_in, const int* in_sizes, int n_in,
                              void* d_out, int out_size, void* d_ws, size_t ws_size,
                              hipStream_t stream)
{
    const float* x      = (const float*)d_in[0];
    const float* fqk_wQ = (const float*)d_in[1];
    const float* fqk_wK = (const float*)d_in[2];
    const float* fv_w   = (const float*)d_in[3];
    const float* rqk_wQ = (const float*)d_in[4];
    const float* rqk_wK = (const float*)d_in[5];
    const float* rv_w   = (const float*)d_in[6];
    const float* fkn_w  = (const float*)d_in[7];
    const float* rkn_w  = (const float*)d_in[8];
    const float* f_qk   = (const float*)d_in[9];
    const float* f_v    = (const float*)d_in[10];
    const float* r_qk   = (const float*)d_in[11];
    const float* r_v    = (const float*)d_in[12];
    const float* f_know = (const float*)d_in[13];
    const float* r_know = (const float*)d_in[14];
    const float* W_O    = (const float*)d_in[15];
    const float* ln1g   = (const float*)d_in[16];
    const float* ln1b   = (const float*)d_in[17];
    const float* ln2g   = (const float*)d_in[18];
    const float* ln2b   = (const float*)d_in[19];
    float* out_f = (float*)d_out;
    (void)ws_size; (void)in_sizes; (void)n_in; (void)out_size;

    // ---- workspace layout (reused slots) ----
    char* ws = (char*)d_ws;
    const size_t MB = 1024 * 1024;
    bf16_t* rqkT   = (bf16_t*)(ws + 0 * MB);    // [1024][2048]  4MB
    bf16_t* rvT    = (bf16_t*)(ws + 4 * MB);    // [1024][2048]  4MB
    bf16_t* rknT   = (bf16_t*)(ws + 8 * MB);    // [1024][1024]  2MB
    bf16_t* woB    = (bf16_t*)(ws + 10 * MB);   // [1024][1024]  2MB
    bf16_t* fknT   = (bf16_t*)(ws + 12 * MB);   // [1024][1024]  2MB
    bf16_t* buf_nx = (bf16_t*)(ws + 14 * MB);   // 8MB: nx -> Vt -> nx2
    bf16_t* buf_y  = (bf16_t*)(ws + 22 * MB);   // 32MB: y[4096][4096] -> QKV[12288][1024]
    char*   buf_s  = ws + 54 * MB;              // 48MB
    bf16_t* fqkT   = (bf16_t*)(buf_s);               // [2048][1024] 4MB (pre-ws only)
    bf16_t* fvT    = (bf16_t*)(buf_s + 4 * MB);      // contiguous -> N=4096 B
    bf16_t* s_q    = (bf16_t*)(buf_s);               // [12288][2048] grouped A
    bf16_t* s_k    = (bf16_t*)(buf_s) + (size_t)4096 * 2048;
    bf16_t* s_v    = (bf16_t*)(buf_s) + (size_t)8192 * 2048;
    bf16_t* attn   = (bf16_t*)(buf_s);               // [4096][1024] 8MB
    float*  P0     = (float*)(buf_s + 16 * MB);      // W_O split-K partials 2x16MB
    float*  P0k    = (float*)(buf_s);                // know split-K partials
    float*  P1k    = (float*)(buf_s + 16 * MB);
    bf16_t* sk2    = (bf16_t*)(buf_s + 32 * MB);     // [4096][1024] 8MB
    bf16_t* Qb     = buf_y;                          // QKV contiguous [12288][1024]
    bf16_t* Kb     = buf_y + (size_t)4096 * 1024;
    bf16_t* Vb     = buf_y + (size_t)8192 * 1024;
    bf16_t* Vt     = buf_nx;                         // [2][1024][2048]

    const dim3 blk256(256), blkT(32, 8);

    // ---- weight conversion ----
    tcast_kernel<<<dim3(R_DIM / 32, D_DIM / 32, N_NEU), blkT, 0, stream>>>(f_qk, fqkT, D_DIM, R_DIM);
    tcast_kernel<<<dim3(R_DIM / 32, D_DIM / 32, N_NEU), blkT, 0, stream>>>(f_v, fvT, D_DIM, R_DIM);
    tcast_kernel<<<dim3(KR_DIM / 32, D_DIM / 32, N_NEU), blkT, 0, stream>>>(f_know, fknT, D_DIM, KR_DIM);
    tcast_kernel<<<dim3(D_DIM / 32, 2048 / 32, 1), blkT, 0, stream>>>(r_qk, rqkT, 2048, D_DIM);
    tcast_kernel<<<dim3(D_DIM / 32, 2048 / 32, 1), blkT, 0, stream>>>(r_v, rvT, 2048, D_DIM);
    tcast_kernel<<<dim3(D_DIM / 32, 1024 / 32, 1), blkT, 0, stream>>>(r_know, rknT, 1024, D_DIM);
    cast_kernel<<<dim3(1024 * 1024 / 4 / 256), blk256, 0, stream>>>(W_O, woB, 1024 * 1024 / 4);

    // ---- LN1 ----
    ln_kernel<<<dim3(ROWS), blk256, 0, stream>>>(x, ln1g, ln1b, buf_nx);

    // ---- fused feature GEMM: y[4096][4096] = nx @ [fqkT;fvT]^T ----
    gemm_kernel<0><<<dim3(32, 32), blk256, 0, stream>>>(buf_nx, fqkT, fqkT, 1 << 30, buf_y, nullptr, 4096, 4096, 1024);

    // ---- fused weighted sums -> sq|sk|sv [12288][2048] ----
    wsf_kernel<<<dim3(ROWS), blk256, 0, stream>>>(buf_y, fqk_wQ, rqk_wQ, fqk_wK, rqk_wK, fv_w, rv_w, s_q, s_k, s_v);

    // ---- grouped restore GEMM: QKV[12288][1024] (768 blocks, B-select) ----
    gemm_kernel<0><<<dim3(8, 96), blk256, 0, stream>>>((bf16_t*)buf_s, rqkT, rvT, 64, buf_y, nullptr, 12288, 1024, 2048);

    // ---- V -> Vt ----
    tbf_kernel<<<dim3(D_DIM / 32, S_LEN / 32, B_DIM), blkT, 0, stream>>>(Vb, Vt, S_LEN, D_DIM);

    // ---- attention (512 balanced two-pass blocks) ----
    fa_kernel<<<dim3(512), blk256, 0, stream>>>(Qb, Kb, Vt, attn);

    // ---- W_O split-K=2: partials P0/P1 (512 blocks) ----
    gemm_kernel<2><<<dim3(8, 32, 2), blk256, 0, stream>>>(attn, woB, woB, 1 << 30, P0, nullptr, 4096, 1024, 1024);

    // ---- LN2 fused: d_out = x + P0 + P1; nx2 = LN(d_out) ----
    ln2x_kernel<<<dim3(ROWS), blk256, 0, stream>>>(x, P0, P0 + (size_t)4096 * 1024, ln2g, ln2b, out_f, buf_nx);

    // ---- know feature split-K=2: partials P0k/P1k (512 blocks) ----
    gemm_kernel<2><<<dim3(8, 32, 2), blk256, 0, stream>>>(buf_nx, fknT, fknT, 1 << 30, P0k, nullptr, 4096, 1024, 1024);

    // ---- know ws (fused reduce) -> sk2 ----
    ws2_kernel<<<dim3(ROWS / 2), blk256, 0, stream>>>(P0k, P1k, fkn_w, rkn_w, sk2);

    // ---- out = sk2 @ rknT^T + x2 -> d_out ----
    gemm_kernel<1><<<dim3(8, 32), blk256, 0, stream>>>(sk2, rknT, rknT, 1 << 30, d_out, out_f, 4096, 1024, 1024);
}

// Round 9
// 302.531 us; speedup vs baseline: 1.1949x; 1.0506x over previous
//
#include <hip/hip_runtime.h>
#include <hip/hip_bf16.h>

// ---------------------------------------------------------------------------
// DAWN block on MI355X.  Round 9:
//  - fa: KVBLK=128 as two fused sub-tiles — one barrier pair / max-tree /
//    P-store per 128 keys (chain-bound => ~2x fewer serial chains).
//    Two-pass balanced blocks: exactly 17 tiles per block.
//  - split-K GEMM partials in bf16 (saves 32MB HBM round-trip).
//  - GEMM: R8 3-buffer counted-vmcnt pipeline (kept).
// ---------------------------------------------------------------------------

typedef __bf16 bf16_t;
typedef __bf16 bf16x4 __attribute__((ext_vector_type(4)));
typedef __bf16 bf16x8 __attribute__((ext_vector_type(8)));
typedef float f32x4 __attribute__((ext_vector_type(4)));

#define B_DIM 2
#define S_LEN 2048
#define D_DIM 1024
#define H_NUM 16
#define DH 64
#define N_NEU 8
#define R_DIM 256
#define KR_DIM 128
#define ROWS (B_DIM * S_LEN)   // 4096

static __device__ __forceinline__ void gl_lds16(const void* g, void* l)
{
    __builtin_amdgcn_global_load_lds(
        (__attribute__((address_space(1))) void*)(g),
        (__attribute__((address_space(3))) void*)(l), 16, 0, 0);
}

// ---------------------------------------------------------------------------
// Batched transpose-cast: in[z][I][J] f32 -> out[z][J][I] bf16.  block (32,8)
// ---------------------------------------------------------------------------
__global__ __launch_bounds__(256)
void tcast_kernel(const float* __restrict__ in, bf16_t* __restrict__ out, int I, int J)
{
    __shared__ float t[32][33];
    const int bJ = blockIdx.x * 32, bI = blockIdx.y * 32;
    const size_t boff = (size_t)blockIdx.z * I * J;
    const int tx = threadIdx.x, ty = threadIdx.y;
#pragma unroll
    for (int i = 0; i < 4; i++)
        t[ty * 4 + i][tx] = in[boff + (size_t)(bI + ty * 4 + i) * J + bJ + tx];
    __syncthreads();
#pragma unroll
    for (int i = 0; i < 4; i++)
        out[boff + (size_t)(bJ + ty * 4 + i) * I + bI + tx] = (bf16_t)t[tx][ty * 4 + i];
}

// bf16 transpose: in[z][I][J] -> out[z][J][I].  block (32,8)
__global__ __launch_bounds__(256)
void tbf_kernel(const bf16_t* __restrict__ in, bf16_t* __restrict__ out, int I, int J)
{
    __shared__ bf16_t t[32][33];
    const int bJ = blockIdx.x * 32, bI = blockIdx.y * 32;
    const size_t boff = (size_t)blockIdx.z * I * J;
    const int tx = threadIdx.x, ty = threadIdx.y;
#pragma unroll
    for (int i = 0; i < 4; i++)
        t[ty * 4 + i][tx] = in[boff + (size_t)(bI + ty * 4 + i) * J + bJ + tx];
    __syncthreads();
#pragma unroll
    for (int i = 0; i < 4; i++)
        out[boff + (size_t)(bJ + ty * 4 + i) * I + bI + tx] = t[tx][ty * 4 + i];
}

// plain cast fp32 -> bf16 (vectorized by 4)
__global__ __launch_bounds__(256)
void cast_kernel(const float* __restrict__ in, bf16_t* __restrict__ out, int n4)
{
    int i = blockIdx.x * 256 + threadIdx.x;
    if (i < n4) {
        float4 v = ((const float4*)in)[i];
        bf16_t* op = out + (size_t)i * 4;
        op[0] = (bf16_t)v.x; op[1] = (bf16_t)v.y; op[2] = (bf16_t)v.z; op[3] = (bf16_t)v.w;
    }
}

// ---------------------------------------------------------------------------
// LayerNorm over D=1024, one row per block. fp32 in, bf16 out.
// ---------------------------------------------------------------------------
__global__ __launch_bounds__(256)
void ln_kernel(const float* __restrict__ x, const float* __restrict__ g,
               const float* __restrict__ beta, bf16_t* __restrict__ out)
{
    __shared__ float red[4];
    const int row = blockIdx.x;
    const int tid = threadIdx.x;
    float4 v = *(const float4*)&x[(size_t)row * D_DIM + tid * 4];

    float s = v.x + v.y + v.z + v.w;
#pragma unroll
    for (int o = 32; o; o >>= 1) s += __shfl_down(s, o);
    if ((tid & 63) == 0) red[tid >> 6] = s;
    __syncthreads();
    float mean = (red[0] + red[1] + red[2] + red[3]) * (1.f / D_DIM);
    __syncthreads();

    float dx = v.x - mean, dy = v.y - mean, dz = v.z - mean, dw = v.w - mean;
    float q = dx * dx + dy * dy + dz * dz + dw * dw;
#pragma unroll
    for (int o = 32; o; o >>= 1) q += __shfl_down(q, o);
    if ((tid & 63) == 0) red[tid >> 6] = q;
    __syncthreads();
    float var = (red[0] + red[1] + red[2] + red[3]) * (1.f / D_DIM);
    float rstd = rsqrtf(var + 1e-5f);

    float4 gv = *(const float4*)&g[tid * 4];
    float4 bv = *(const float4*)&beta[tid * 4];
    bf16_t* op = out + (size_t)row * D_DIM + tid * 4;
    op[0] = (bf16_t)(dx * rstd * gv.x + bv.x);
    op[1] = (bf16_t)(dy * rstd * gv.y + bv.y);
    op[2] = (bf16_t)(dz * rstd * gv.z + bv.z);
    op[3] = (bf16_t)(dw * rstd * gv.w + bv.w);
}

// ---------------------------------------------------------------------------
// LN2 with fused split-K reduce (bf16 partials) + residual:
//   sum = x + P0 + P1 -> outf (fp32), then LN(sum) -> bf16 outn.
// ---------------------------------------------------------------------------
__global__ __launch_bounds__(256)
void ln2x_kernel(const float* __restrict__ x, const bf16_t* __restrict__ P0,
                 const bf16_t* __restrict__ P1, const float* __restrict__ g,
                 const float* __restrict__ beta, float* __restrict__ outf,
                 bf16_t* __restrict__ outn)
{
    __shared__ float red[4];
    const int row = blockIdx.x;
    const int tid = threadIdx.x;
    const size_t base = (size_t)row * D_DIM + tid * 4;
    float4 v  = *(const float4*)&x[base];
    bf16x4 p0 = *(const bf16x4*)&P0[base];
    bf16x4 p1 = *(const bf16x4*)&P1[base];
    v.x += (float)p0[0] + (float)p1[0];
    v.y += (float)p0[1] + (float)p1[1];
    v.z += (float)p0[2] + (float)p1[2];
    v.w += (float)p0[3] + (float)p1[3];
    *(float4*)&outf[base] = v;

    float s = v.x + v.y + v.z + v.w;
#pragma unroll
    for (int o = 32; o; o >>= 1) s += __shfl_down(s, o);
    if ((tid & 63) == 0) red[tid >> 6] = s;
    __syncthreads();
    float mean = (red[0] + red[1] + red[2] + red[3]) * (1.f / D_DIM);
    __syncthreads();

    float dx = v.x - mean, dy = v.y - mean, dz = v.z - mean, dw = v.w - mean;
    float q = dx * dx + dy * dy + dz * dz + dw * dw;
#pragma unroll
    for (int o = 32; o; o >>= 1) q += __shfl_down(q, o);
    if ((tid & 63) == 0) red[tid >> 6] = q;
    __syncthreads();
    float var = (red[0] + red[1] + red[2] + red[3]) * (1.f / D_DIM);
    float rstd = rsqrtf(var + 1e-5f);

    float4 gv = *(const float4*)&g[tid * 4];
    float4 bv = *(const float4*)&beta[tid * 4];
    bf16_t* op = outn + base;
    op[0] = (bf16_t)(dx * rstd * gv.x + bv.x);
    op[1] = (bf16_t)(dy * rstd * gv.y + bv.y);
    op[2] = (bf16_t)(dz * rstd * gv.z + bv.z);
    op[3] = (bf16_t)(dw * rstd * gv.w + bv.w);
}

// ---------------------------------------------------------------------------
// Fused weighted-sum for Q/K/V: reads y row once, writes sq, sk, sv.
// ---------------------------------------------------------------------------
__global__ __launch_bounds__(256)
void wsf_kernel(const bf16_t* __restrict__ y,
                const float* __restrict__ wfQ, const float* __restrict__ wrQ,
                const float* __restrict__ wfK, const float* __restrict__ wrK,
                const float* __restrict__ wfV, const float* __restrict__ wrV,
                bf16_t* __restrict__ sq, bf16_t* __restrict__ sk, bf16_t* __restrict__ sv)
{
    const int r = threadIdx.x;
    const int row = blockIdx.x;
    const bf16_t* yrow = y + (size_t)row * 4096;
    const float* fQ = wfQ + row * N_NEU;
    const float* fK = wfK + row * N_NEU;
    const float* fV = wfV + row * N_NEU;
    float aQ = 0.f, aK = 0.f, aV = 0.f;
#pragma unroll
    for (int n = 0; n < N_NEU; n++) {
        float yq = (float)yrow[n * R_DIM + r];
        float yv = (float)yrow[2048 + n * R_DIM + r];
        aQ += fQ[n] * yq;
        aK += fK[n] * yq;
        aV += fV[n] * yv;
    }
    const float* rQ = wrQ + row * N_NEU;
    const float* rK = wrK + row * N_NEU;
    const float* rV = wrV + row * N_NEU;
    const size_t rb = (size_t)row * 2048;
#pragma unroll
    for (int n = 0; n < N_NEU; n++) {
        sq[rb + n * R_DIM + r] = (bf16_t)(rQ[n] * aQ);
        sk[rb + n * R_DIM + r] = (bf16_t)(rK[n] * aK);
        sv[rb + n * R_DIM + r] = (bf16_t)(rV[n] * aV);
    }
}

// know-path ws with fused split-K reduce (bf16 partials), KR=128.
__global__ __launch_bounds__(256)
void ws2_kernel(const bf16_t* __restrict__ P0, const bf16_t* __restrict__ P1,
                const float* __restrict__ wf, const float* __restrict__ wr,
                bf16_t* __restrict__ sout)
{
    const int lr = threadIdx.x >> 7;
    const int r  = threadIdx.x & 127;
    const int row = blockIdx.x * 2 + lr;
    const size_t rb = (size_t)row * (N_NEU * KR_DIM);
    const float* wfp = wf + row * N_NEU;
    const float* wrp = wr + row * N_NEU;
    float acc = 0.f;
#pragma unroll
    for (int n = 0; n < N_NEU; n++) {
        size_t i = rb + n * KR_DIM + r;
        acc += wfp[n] * ((float)P0[i] + (float)P1[i]);
    }
    bf16_t* srow = sout + rb;
#pragma unroll
    for (int n = 0; n < N_NEU; n++) srow[n * KR_DIM + r] = (bf16_t)(wrp[n] * acc);
}

// ---------------------------------------------------------------------------
// GEMM, 3-buffer pipeline with counted vmcnt (T3+T4).
// C[M,N] = A[M,K] @ Bsel[N,K]^T.  128x128 tile, BK=32.
// EPI=0: bf16 C.  EPI=1: fp32 C = acc + resid.  EPI=2: bf16 partial per
// blockIdx.z (split-K=2) at Cout + z*M*N.
// ---------------------------------------------------------------------------
template<int EPI>
__global__ __launch_bounds__(256)
void gemm_kernel(const bf16_t* __restrict__ A, const bf16_t* __restrict__ Bt,
                 const bf16_t* __restrict__ Bt2, int splitMy,
                 void* Cout, const float* resid, int M, int N, int K)
{
    __shared__ bf16_t As[3][128][32];
    __shared__ bf16_t Bs[3][128][32];
    const int tid = threadIdx.x;
    const int l = tid & 63, w = tid >> 6;
    const int wr = w >> 1, wc = w & 1;

    // XCD-chunked swizzle (bijective when grid multiple of 8)
    const int nbxy = gridDim.x * gridDim.y;
    int bid = blockIdx.y * gridDim.x + blockIdx.x;
    if ((nbxy & 7) == 0) bid = (bid & 7) * (nbxy >> 3) + (bid >> 3);
    const int bx = bid % gridDim.x, by = bid / gridDim.x;

    const int m0 = by * 128, n0 = bx * 128;
    const bf16_t* Bsel = (by < splitMy) ? Bt : Bt2;

    int kbeg = 0, kend = K;
    if constexpr (EPI == 2) { const int half = K >> 1; kbeg = blockIdx.z * half; kend = kbeg + half; }

    const int srow = l >> 2;
    const int scol = (l & 3) * 8;
    const bf16_t* Ag0 = A    + (size_t)(m0 + w * 32 + srow) * K + scol;
    const bf16_t* Ag1 = Ag0 + (size_t)16 * K;
    const bf16_t* Bg0 = Bsel + (size_t)(n0 + w * 32 + srow) * K + scol;
    const bf16_t* Bg1 = Bg0 + (size_t)16 * K;

    auto stage = [&](int buf, int k0) {
        char* Asb = (char*)&As[buf][0][0] + w * 2048;
        char* Bsb = (char*)&Bs[buf][0][0] + w * 2048;
        gl_lds16(Ag0 + k0, Asb);
        gl_lds16(Ag1 + k0, Asb + 1024);
        gl_lds16(Bg0 + k0, Bsb);
        gl_lds16(Bg1 + k0, Bsb + 1024);
    };

    f32x4 acc[4][4];
    const f32x4 zero = {0.f, 0.f, 0.f, 0.f};
#pragma unroll
    for (int i = 0; i < 4; i++)
#pragma unroll
        for (int j = 0; j < 4; j++) acc[i][j] = zero;

    const int fr = l & 15;
    const int fk = (l >> 4) * 8;

    // prologue: stage tiles 0 and 1 (all our K >= 512, nK >= 16)
    stage(0, kbeg);
    stage(1, kbeg + 32);

    const int nK = (kend - kbeg) >> 5;
    for (int it = 0; it < nK; ++it) {
        if (it + 1 < nK) {
            asm volatile("s_waitcnt vmcnt(4)" ::: "memory");
        } else {
            asm volatile("s_waitcnt vmcnt(0)" ::: "memory");
        }
        __builtin_amdgcn_s_barrier();
        __builtin_amdgcn_sched_barrier(0);   // pin: nothing crosses the barrier

        const int cur = it % 3;
        bf16x8 af[4], bv[4];
#pragma unroll
        for (int i = 0; i < 4; i++) af[i] = *(const bf16x8*)&As[cur][wr * 64 + i * 16 + fr][fk];
#pragma unroll
        for (int i = 0; i < 4; i++) bv[i] = *(const bf16x8*)&Bs[cur][wc * 64 + i * 16 + fr][fk];

        if (it + 2 < nK) stage((it + 2) % 3, kbeg + (it + 2) * 32);

        __builtin_amdgcn_s_setprio(1);
#pragma unroll
        for (int mi = 0; mi < 4; mi++)
#pragma unroll
            for (int ni = 0; ni < 4; ni++)
                acc[mi][ni] = __builtin_amdgcn_mfma_f32_16x16x32_bf16(af[mi], bv[ni], acc[mi][ni], 0, 0, 0);
        __builtin_amdgcn_s_setprio(0);
    }

    const int orow = (l >> 4) * 4;
    const int ocol = l & 15;
#pragma unroll
    for (int mi = 0; mi < 4; mi++)
#pragma unroll
        for (int ni = 0; ni < 4; ni++)
#pragma unroll
            for (int j = 0; j < 4; j++) {
                int row = m0 + wr * 64 + mi * 16 + orow + j;
                int col = n0 + wc * 64 + ni * 16 + ocol;
                size_t idx = (size_t)row * N + col;
                if constexpr (EPI == 0) {
                    ((bf16_t*)Cout)[idx] = (bf16_t)acc[mi][ni][j];
                } else if constexpr (EPI == 1) {
                    ((float*)Cout)[idx] = acc[mi][ni][j] + resid[idx];
                } else {
                    ((bf16_t*)Cout)[(size_t)blockIdx.z * M * N + idx] = (bf16_t)acc[mi][ni][j];
                }
            }
}

// ---------------------------------------------------------------------------
// Causal flash attention, KVBLK=128 (two fused 64-key sub-tiles).
// Q/K/O: [B*S][1024] bf16 (head h = cols h*64..+64).
// Vt: [B][1024][2048] bf16 (pre-transposed V).
// 512 blocks: xcd=bid&7, slot=bid>>3 (0..63), head=slot&3, jq=slot>>2 (0..15).
// Block runs q-tiles (31-jq) then (jq); 128-key tiles per block =
// ((31-jq)>>1)+1 + ((jq>>1))+1 = 17 for every jq — perfectly balanced.
// One barrier pair / max-tree / rescale / P-store phase per 128 keys.
// exp2 softmax, defer-max (T13), MFMA l-sum, mask only on last tile.
// ---------------------------------------------------------------------------
__global__ __launch_bounds__(256)
void fa_kernel(const bf16_t* __restrict__ Q, const bf16_t* __restrict__ K,
               const bf16_t* __restrict__ Vt, bf16_t* __restrict__ O)
{
    __shared__ bf16_t Ks[128][72];
    __shared__ bf16_t Vs[64][136];
    __shared__ bf16_t Ps[4][16][136];

    const int tid = threadIdx.x;
    const int l = tid & 63, w = tid >> 6;

    const int bid  = blockIdx.x;
    const int xcd  = bid & 7;
    const int slot = bid >> 3;          // 0..63
    const int head = slot & 3;
    const int jq   = slot >> 2;         // 0..15
    const int bh   = xcd * 4 + head;
    const int b = bh >> 4, h = bh & 15;

    const bf16_t* Qp = Q + (size_t)b * S_LEN * D_DIM + h * DH;
    const bf16_t* Kp = K + (size_t)b * S_LEN * D_DIM + h * DH;
    const bf16_t* Vp = Vt + (size_t)b * D_DIM * S_LEN + (size_t)h * DH * S_LEN;

    const int fr = l & 15, fg = l >> 4, fk = fg * 8;
    const int srow = tid >> 2;          // 0..63
    const int scol = (tid & 3) * 16;    // 0,16,32,48
    const bf16_t* Kst = Kp + (size_t)srow * D_DIM + scol;
    const bf16_t* Vst = Vp + (size_t)srow * S_LEN + scol;

    bf16x8 ones8;
#pragma unroll
    for (int i = 0; i < 8; i++) ones8[i] = (bf16_t)1.f;

    const f32x4 zero = {0.f, 0.f, 0.f, 0.f};
    const float C_LOG2 = 0.125f * 1.44269504f;   // 1/sqrt(DH) * log2(e)

    for (int pass = 0; pass < 2; ++pass) {
        const int qb = pass ? jq : (31 - jq);    // long pass first
        const int q0 = qb * 64;
        const int nt = (qb >> 1) + 1;            // 128-key tiles

        bf16x8 qf[2];
#pragma unroll
        for (int ks = 0; ks < 2; ks++)
            qf[ks] = *(const bf16x8*)(Qp + (size_t)(q0 + w * 16 + fr) * D_DIM + ks * 32 + fk);

        f32x4 o[4];
        f32x4 la = zero;
        float m_r[4];
#pragma unroll
        for (int j = 0; j < 4; j++) { o[j] = zero; m_r[j] = -1e30f; }

        // prologue: issue loads for tile 0 (keys 0..127; rows always in-bounds)
        uint4 kva = *(const uint4*)(Kst);
        uint4 kvb = *(const uint4*)(Kst + 8);
        uint4 kvc = *(const uint4*)(Kst + (size_t)64 * D_DIM);
        uint4 kvd = *(const uint4*)(Kst + (size_t)64 * D_DIM + 8);
        uint4 vva = *(const uint4*)(Vst);
        uint4 vvb = *(const uint4*)(Vst + 8);
        uint4 vvc = *(const uint4*)(Vst + 64);
        uint4 vvd = *(const uint4*)(Vst + 72);

        for (int t = 0; t < nt; t++) {
            const int k0 = t * 128;
            __syncthreads();              // previous tile's reads complete
            *(uint4*)&Ks[srow][scol]          = kva;
            *(uint4*)&Ks[srow][scol + 8]      = kvb;
            *(uint4*)&Ks[64 + srow][scol]     = kvc;
            *(uint4*)&Ks[64 + srow][scol + 8] = kvd;
            *(uint4*)&Vs[srow][scol]          = vva;
            *(uint4*)&Vs[srow][scol + 8]      = vvb;
            *(uint4*)&Vs[srow][64 + scol]     = vvc;
            *(uint4*)&Vs[srow][64 + scol + 8] = vvd;
            __syncthreads();

            if (t + 1 < nt) {             // T14: issue next tile's loads now
                const int kn = k0 + 128;
                kva = *(const uint4*)(Kst + (size_t)kn * D_DIM);
                kvb = *(const uint4*)(Kst + (size_t)kn * D_DIM + 8);
                kvc = *(const uint4*)(Kst + (size_t)(kn + 64) * D_DIM);
                kvd = *(const uint4*)(Kst + (size_t)(kn + 64) * D_DIM + 8);
                vva = *(const uint4*)(Vst + kn);
                vvb = *(const uint4*)(Vst + kn + 8);
                vvc = *(const uint4*)(Vst + kn + 64);
                vvd = *(const uint4*)(Vst + kn + 72);
            }

            // ---- QK^T: 16 q-rows x 128 keys (2 independent sub-tiles) ----
            f32x4 sc[2][4];
#pragma unroll
            for (int s2 = 0; s2 < 2; s2++)
#pragma unroll
                for (int ni = 0; ni < 4; ni++) sc[s2][ni] = zero;
            __builtin_amdgcn_s_setprio(1);
#pragma unroll
            for (int ks = 0; ks < 2; ks++) {
#pragma unroll
                for (int s2 = 0; s2 < 2; s2++)
#pragma unroll
                    for (int ni = 0; ni < 4; ni++) {
                        bf16x8 kf = *(const bf16x8*)&Ks[s2 * 64 + ni * 16 + fr][ks * 32 + fk];
                        sc[s2][ni] = __builtin_amdgcn_mfma_f32_16x16x32_bf16(qf[ks], kf, sc[s2][ni], 0, 0, 0);
                    }
            }
            __builtin_amdgcn_s_setprio(0);

            // ---- scale to log2 domain (+ causal mask only on last tile) ----
            float p[2][4][4];
            if (t == nt - 1) {
#pragma unroll
                for (int s2 = 0; s2 < 2; s2++)
#pragma unroll
                    for (int ni = 0; ni < 4; ni++) {
                        const int key = k0 + s2 * 64 + ni * 16 + fr;
#pragma unroll
                        for (int j = 0; j < 4; j++) {
                            const int qg = q0 + w * 16 + fg * 4 + j;
                            p[s2][ni][j] = (key <= qg) ? sc[s2][ni][j] * C_LOG2 : -1e30f;
                        }
                    }
            } else {
#pragma unroll
                for (int s2 = 0; s2 < 2; s2++)
#pragma unroll
                    for (int ni = 0; ni < 4; ni++)
#pragma unroll
                        for (int j = 0; j < 4; j++)
                            p[s2][ni][j] = sc[s2][ni][j] * C_LOG2;
            }

            // ---- online softmax over 128 keys (one tree per tile) ----
#pragma unroll
            for (int j = 0; j < 4; j++) {
                float rmax = p[0][0][j];
#pragma unroll
                for (int s2 = 0; s2 < 2; s2++)
#pragma unroll
                    for (int ni = 0; ni < 4; ni++) rmax = fmaxf(rmax, p[s2][ni][j]);
#pragma unroll
                for (int d = 1; d < 16; d <<= 1) rmax = fmaxf(rmax, __shfl_xor(rmax, d));
                if (rmax > m_r[j] + 8.f) {         // defer-max (T13)
                    float scale = exp2f(m_r[j] - rmax);
                    la[j] *= scale;
#pragma unroll
                    for (int nc = 0; nc < 4; nc++) o[nc][j] *= scale;
                    m_r[j] = rmax;
                }
#pragma unroll
                for (int s2 = 0; s2 < 2; s2++)
#pragma unroll
                    for (int ni = 0; ni < 4; ni++)
                        p[s2][ni][j] = exp2f(p[s2][ni][j] - m_r[j]);   // <= 2^8
            }

            // ---- P -> A-layout via per-wave LDS bounce (128 cols) ----
#pragma unroll
            for (int s2 = 0; s2 < 2; s2++)
#pragma unroll
                for (int ni = 0; ni < 4; ni++)
#pragma unroll
                    for (int j = 0; j < 4; j++)
                        Ps[w][fg * 4 + j][s2 * 64 + ni * 16 + fr] = (bf16_t)p[s2][ni][j];

            // ---- PV + l-sum over 128 keys (4 ks steps) ----
            __builtin_amdgcn_s_setprio(1);
#pragma unroll
            for (int ks = 0; ks < 4; ks++) {
                bf16x8 pa = *(const bf16x8*)&Ps[w][fr][ks * 32 + fk];
                la = __builtin_amdgcn_mfma_f32_16x16x32_bf16(pa, ones8, la, 0, 0, 0);
#pragma unroll
                for (int nc = 0; nc < 4; nc++) {
                    bf16x8 vf = *(const bf16x8*)&Vs[nc * 16 + fr][ks * 32 + fk];
                    o[nc] = __builtin_amdgcn_mfma_f32_16x16x32_bf16(pa, vf, o[nc], 0, 0, 0);
                }
            }
            __builtin_amdgcn_s_setprio(0);
        }

        // ---- epilogue for this q-tile ----
#pragma unroll
        for (int j = 0; j < 4; j++) {
            const float inv = 1.f / la[j];
            const int q = q0 + w * 16 + fg * 4 + j;
            bf16_t* op = O + (size_t)(b * S_LEN + q) * D_DIM + h * DH;
#pragma unroll
            for (int nc = 0; nc < 4; nc++)
                op[nc * 16 + fr] = (bf16_t)(o[nc][j] * inv);
        }
    }
}

// ---------------------------------------------------------------------------
extern "C" void kernel_launch(void* const* d_in, const int* in_sizes, int n_in,
                              void* d_out, int out_size, void* d_ws, size_t ws_size,
                              hipStream_t stream)
{
    const float* x      = (const float*)d_in[0];
    const float* fqk_wQ = (const float*)d_in[1];
    const float* fqk_wK = (const float*)d_in[2];
    const float* fv_w   = (const float*)d_in[3];
    const float* rqk_wQ = (const float*)d_in[4];
    const float* rqk_wK = (const float*)d_in[5];
    const float* rv_w   = (const float*)d_in[6];
    const float* fkn_w  = (const float*)d_in[7];
    const float* rkn_w  = (const float*)d_in[8];
    const float* f_qk   = (const float*)d_in[9];
    const float* f_v    = (const float*)d_in[10];
    const float* r_qk   = (const float*)d_in[11];
    const float* r_v    = (const float*)d_in[12];
    const float* f_know = (const float*)d_in[13];
    const float* r_know = (const float*)d_in[14];
    const float* W_O    = (const float*)d_in[15];
    const float* ln1g   = (const float*)d_in[16];
    const float* ln1b   = (const float*)d_in[17];
    const float* ln2g   = (const float*)d_in[18];
    const float* ln2b   = (const float*)d_in[19];
    float* out_f = (float*)d_out;
    (void)ws_size; (void)in_sizes; (void)n_in; (void)out_size;

    // ---- workspace layout (reused slots) ----
    char* ws = (char*)d_ws;
    const size_t MB = 1024 * 1024;
    bf16_t* rqkT   = (bf16_t*)(ws + 0 * MB);    // [1024][2048]  4MB
    bf16_t* rvT    = (bf16_t*)(ws + 4 * MB);    // [1024][2048]  4MB
    bf16_t* rknT   = (bf16_t*)(ws + 8 * MB);    // [1024][1024]  2MB
    bf16_t* woB    = (bf16_t*)(ws + 10 * MB);   // [1024][1024]  2MB
    bf16_t* fknT   = (bf16_t*)(ws + 12 * MB);   // [1024][1024]  2MB
    bf16_t* buf_nx = (bf16_t*)(ws + 14 * MB);   // 8MB: nx -> Vt -> nx2
    bf16_t* buf_y  = (bf16_t*)(ws + 22 * MB);   // 32MB: y[4096][4096] -> QKV[12288][1024]
    char*   buf_s  = ws + 54 * MB;              // 48MB
    bf16_t* fqkT   = (bf16_t*)(buf_s);               // [2048][1024] 4MB (pre-ws only)
    bf16_t* fvT    = (bf16_t*)(buf_s + 4 * MB);      // contiguous -> N=4096 B
    bf16_t* s_q    = (bf16_t*)(buf_s);               // [12288][2048] grouped A
    bf16_t* s_k    = (bf16_t*)(buf_s) + (size_t)4096 * 2048;
    bf16_t* s_v    = (bf16_t*)(buf_s) + (size_t)8192 * 2048;
    bf16_t* attn   = (bf16_t*)(buf_s);               // [4096][1024] 8MB
    bf16_t* P0     = (bf16_t*)(buf_s + 16 * MB);     // W_O bf16 partials 2x8MB [16,32MB)
    bf16_t* P0k    = (bf16_t*)(buf_s);               // know bf16 partials 2x8MB [0,16MB)
    bf16_t* sk2    = (bf16_t*)(buf_s + 32 * MB);     // [4096][1024] 8MB
    bf16_t* Qb     = buf_y;                          // QKV contiguous [12288][1024]
    bf16_t* Kb     = buf_y + (size_t)4096 * 1024;
    bf16_t* Vb     = buf_y + (size_t)8192 * 1024;
    bf16_t* Vt     = buf_nx;                         // [2][1024][2048]

    const dim3 blk256(256), blkT(32, 8);

    // ---- weight conversion ----
    tcast_kernel<<<dim3(R_DIM / 32, D_DIM / 32, N_NEU), blkT, 0, stream>>>(f_qk, fqkT, D_DIM, R_DIM);
    tcast_kernel<<<dim3(R_DIM / 32, D_DIM / 32, N_NEU), blkT, 0, stream>>>(f_v, fvT, D_DIM, R_DIM);
    tcast_kernel<<<dim3(KR_DIM / 32, D_DIM / 32, N_NEU), blkT, 0, stream>>>(f_know, fknT, D_DIM, KR_DIM);
    tcast_kernel<<<dim3(D_DIM / 32, 2048 / 32, 1), blkT, 0, stream>>>(r_qk, rqkT, 2048, D_DIM);
    tcast_kernel<<<dim3(D_DIM / 32, 2048 / 32, 1), blkT, 0, stream>>>(r_v, rvT, 2048, D_DIM);
    tcast_kernel<<<dim3(D_DIM / 32, 1024 / 32, 1), blkT, 0, stream>>>(r_know, rknT, 1024, D_DIM);
    cast_kernel<<<dim3(1024 * 1024 / 4 / 256), blk256, 0, stream>>>(W_O, woB, 1024 * 1024 / 4);

    // ---- LN1 ----
    ln_kernel<<<dim3(ROWS), blk256, 0, stream>>>(x, ln1g, ln1b, buf_nx);

    // ---- fused feature GEMM: y[4096][4096] = nx @ [fqkT;fvT]^T ----
    gemm_kernel<0><<<dim3(32, 32), blk256, 0, stream>>>(buf_nx, fqkT, fqkT, 1 << 30, buf_y, nullptr, 4096, 4096, 1024);

    // ---- fused weighted sums -> sq|sk|sv [12288][2048] ----
    wsf_kernel<<<dim3(ROWS), blk256, 0, stream>>>(buf_y, fqk_wQ, rqk_wQ, fqk_wK, rqk_wK, fv_w, rv_w, s_q, s_k, s_v);

    // ---- grouped restore GEMM: QKV[12288][1024] (768 blocks, B-select) ----
    gemm_kernel<0><<<dim3(8, 96), blk256, 0, stream>>>((bf16_t*)buf_s, rqkT, rvT, 64, buf_y, nullptr, 12288, 1024, 2048);

    // ---- V -> Vt ----
    tbf_kernel<<<dim3(D_DIM / 32, S_LEN / 32, B_DIM), blkT, 0, stream>>>(Vb, Vt, S_LEN, D_DIM);

    // ---- attention (512 balanced two-pass blocks, KVBLK=128) ----
    fa_kernel<<<dim3(512), blk256, 0, stream>>>(Qb, Kb, Vt, attn);

    // ---- W_O split-K=2: bf16 partials (512 blocks) ----
    gemm_kernel<2><<<dim3(8, 32, 2), blk256, 0, stream>>>(attn, woB, woB, 1 << 30, P0, nullptr, 4096, 1024, 1024);

    // ---- LN2 fused: d_out = x + P0 + P1; nx2 = LN(d_out) ----
    ln2x_kernel<<<dim3(ROWS), blk256, 0, stream>>>(x, P0, P0 + (size_t)4096 * 1024, ln2g, ln2b, out_f, buf_nx);

    // ---- know feature split-K=2: bf16 partials (512 blocks) ----
    gemm_kernel<2><<<dim3(8, 32, 2), blk256, 0, stream>>>(buf_nx, fknT, fknT, 1 << 30, P0k, nullptr, 4096, 1024, 1024);

    // ---- know ws (fused reduce) -> sk2 ----
    ws2_kernel<<<dim3(ROWS / 2), blk256, 0, stream>>>(P0k, P0k + (size_t)4096 * 1024, fkn_w, rkn_w, sk2);

    // ---- out = sk2 @ rknT^T + x2 -> d_out ----
    gemm_kernel<1><<<dim3(8, 32), blk256, 0, stream>>>(sk2, rknT, rknT, 1 << 30, d_out, out_f, 4096, 1024, 1024);
}

// Round 10
// 301.976 us; speedup vs baseline: 1.1970x; 1.0018x over previous
//
#include <hip/hip_runtime.h>
#include <hip/hip_bf16.h>

// ---------------------------------------------------------------------------
// DAWN block on MI355X.  Round 10:
//  - GEMM: T2 LDS XOR-swizzle (colbyte ^= (row&6)<<3) — 8-way ds_read_b128
//    bank conflict -> 2-way.  Linear gl_lds dest + pre-swizzled global source
//    + swizzled read (involution, 16B aligned).  Counted-vmcnt 3-buffer
//    pipeline kept from R8/R9.
//  - fa, aux: unchanged from R9.
// ---------------------------------------------------------------------------

typedef __bf16 bf16_t;
typedef __bf16 bf16x4 __attribute__((ext_vector_type(4)));
typedef __bf16 bf16x8 __attribute__((ext_vector_type(8)));
typedef float f32x4 __attribute__((ext_vector_type(4)));

#define B_DIM 2
#define S_LEN 2048
#define D_DIM 1024
#define H_NUM 16
#define DH 64
#define N_NEU 8
#define R_DIM 256
#define KR_DIM 128
#define ROWS (B_DIM * S_LEN)   // 4096

static __device__ __forceinline__ void gl_lds16(const void* g, void* l)
{
    __builtin_amdgcn_global_load_lds(
        (__attribute__((address_space(1))) void*)(g),
        (__attribute__((address_space(3))) void*)(l), 16, 0, 0);
}

// ---------------------------------------------------------------------------
// Batched transpose-cast: in[z][I][J] f32 -> out[z][J][I] bf16.  block (32,8)
// ---------------------------------------------------------------------------
__global__ __launch_bounds__(256)
void tcast_kernel(const float* __restrict__ in, bf16_t* __restrict__ out, int I, int J)
{
    __shared__ float t[32][33];
    const int bJ = blockIdx.x * 32, bI = blockIdx.y * 32;
    const size_t boff = (size_t)blockIdx.z * I * J;
    const int tx = threadIdx.x, ty = threadIdx.y;
#pragma unroll
    for (int i = 0; i < 4; i++)
        t[ty * 4 + i][tx] = in[boff + (size_t)(bI + ty * 4 + i) * J + bJ + tx];
    __syncthreads();
#pragma unroll
    for (int i = 0; i < 4; i++)
        out[boff + (size_t)(bJ + ty * 4 + i) * I + bI + tx] = (bf16_t)t[tx][ty * 4 + i];
}

// bf16 transpose: in[z][I][J] -> out[z][J][I].  block (32,8)
__global__ __launch_bounds__(256)
void tbf_kernel(const bf16_t* __restrict__ in, bf16_t* __restrict__ out, int I, int J)
{
    __shared__ bf16_t t[32][33];
    const int bJ = blockIdx.x * 32, bI = blockIdx.y * 32;
    const size_t boff = (size_t)blockIdx.z * I * J;
    const int tx = threadIdx.x, ty = threadIdx.y;
#pragma unroll
    for (int i = 0; i < 4; i++)
        t[ty * 4 + i][tx] = in[boff + (size_t)(bI + ty * 4 + i) * J + bJ + tx];
    __syncthreads();
#pragma unroll
    for (int i = 0; i < 4; i++)
        out[boff + (size_t)(bJ + ty * 4 + i) * I + bI + tx] = t[tx][ty * 4 + i];
}

// plain cast fp32 -> bf16 (vectorized by 4)
__global__ __launch_bounds__(256)
void cast_kernel(const float* __restrict__ in, bf16_t* __restrict__ out, int n4)
{
    int i = blockIdx.x * 256 + threadIdx.x;
    if (i < n4) {
        float4 v = ((const float4*)in)[i];
        bf16_t* op = out + (size_t)i * 4;
        op[0] = (bf16_t)v.x; op[1] = (bf16_t)v.y; op[2] = (bf16_t)v.z; op[3] = (bf16_t)v.w;
    }
}

// ---------------------------------------------------------------------------
// LayerNorm over D=1024, one row per block. fp32 in, bf16 out.
// ---------------------------------------------------------------------------
__global__ __launch_bounds__(256)
void ln_kernel(const float* __restrict__ x, const float* __restrict__ g,
               const float* __restrict__ beta, bf16_t* __restrict__ out)
{
    __shared__ float red[4];
    const int row = blockIdx.x;
    const int tid = threadIdx.x;
    float4 v = *(const float4*)&x[(size_t)row * D_DIM + tid * 4];

    float s = v.x + v.y + v.z + v.w;
#pragma unroll
    for (int o = 32; o; o >>= 1) s += __shfl_down(s, o);
    if ((tid & 63) == 0) red[tid >> 6] = s;
    __syncthreads();
    float mean = (red[0] + red[1] + red[2] + red[3]) * (1.f / D_DIM);
    __syncthreads();

    float dx = v.x - mean, dy = v.y - mean, dz = v.z - mean, dw = v.w - mean;
    float q = dx * dx + dy * dy + dz * dz + dw * dw;
#pragma unroll
    for (int o = 32; o; o >>= 1) q += __shfl_down(q, o);
    if ((tid & 63) == 0) red[tid >> 6] = q;
    __syncthreads();
    float var = (red[0] + red[1] + red[2] + red[3]) * (1.f / D_DIM);
    float rstd = rsqrtf(var + 1e-5f);

    float4 gv = *(const float4*)&g[tid * 4];
    float4 bv = *(const float4*)&beta[tid * 4];
    bf16_t* op = out + (size_t)row * D_DIM + tid * 4;
    op[0] = (bf16_t)(dx * rstd * gv.x + bv.x);
    op[1] = (bf16_t)(dy * rstd * gv.y + bv.y);
    op[2] = (bf16_t)(dz * rstd * gv.z + bv.z);
    op[3] = (bf16_t)(dw * rstd * gv.w + bv.w);
}

// ---------------------------------------------------------------------------
// LN2 with fused split-K reduce (bf16 partials) + residual:
//   sum = x + P0 + P1 -> outf (fp32), then LN(sum) -> bf16 outn.
// ---------------------------------------------------------------------------
__global__ __launch_bounds__(256)
void ln2x_kernel(const float* __restrict__ x, const bf16_t* __restrict__ P0,
                 const bf16_t* __restrict__ P1, const float* __restrict__ g,
                 const float* __restrict__ beta, float* __restrict__ outf,
                 bf16_t* __restrict__ outn)
{
    __shared__ float red[4];
    const int row = blockIdx.x;
    const int tid = threadIdx.x;
    const size_t base = (size_t)row * D_DIM + tid * 4;
    float4 v  = *(const float4*)&x[base];
    bf16x4 p0 = *(const bf16x4*)&P0[base];
    bf16x4 p1 = *(const bf16x4*)&P1[base];
    v.x += (float)p0[0] + (float)p1[0];
    v.y += (float)p0[1] + (float)p1[1];
    v.z += (float)p0[2] + (float)p1[2];
    v.w += (float)p0[3] + (float)p1[3];
    *(float4*)&outf[base] = v;

    float s = v.x + v.y + v.z + v.w;
#pragma unroll
    for (int o = 32; o; o >>= 1) s += __shfl_down(s, o);
    if ((tid & 63) == 0) red[tid >> 6] = s;
    __syncthreads();
    float mean = (red[0] + red[1] + red[2] + red[3]) * (1.f / D_DIM);
    __syncthreads();

    float dx = v.x - mean, dy = v.y - mean, dz = v.z - mean, dw = v.w - mean;
    float q = dx * dx + dy * dy + dz * dz + dw * dw;
#pragma unroll
    for (int o = 32; o; o >>= 1) q += __shfl_down(q, o);
    if ((tid & 63) == 0) red[tid >> 6] = q;
    __syncthreads();
    float var = (red[0] + red[1] + red[2] + red[3]) * (1.f / D_DIM);
    float rstd = rsqrtf(var + 1e-5f);

    float4 gv = *(const float4*)&g[tid * 4];
    float4 bv = *(const float4*)&beta[tid * 4];
    bf16_t* op = outn + base;
    op[0] = (bf16_t)(dx * rstd * gv.x + bv.x);
    op[1] = (bf16_t)(dy * rstd * gv.y + bv.y);
    op[2] = (bf16_t)(dz * rstd * gv.z + bv.z);
    op[3] = (bf16_t)(dw * rstd * gv.w + bv.w);
}

// ---------------------------------------------------------------------------
// Fused weighted-sum for Q/K/V: reads y row once, writes sq, sk, sv.
// ---------------------------------------------------------------------------
__global__ __launch_bounds__(256)
void wsf_kernel(const bf16_t* __restrict__ y,
                const float* __restrict__ wfQ, const float* __restrict__ wrQ,
                const float* __restrict__ wfK, const float* __restrict__ wrK,
                const float* __restrict__ wfV, const float* __restrict__ wrV,
                bf16_t* __restrict__ sq, bf16_t* __restrict__ sk, bf16_t* __restrict__ sv)
{
    const int r = threadIdx.x;
    const int row = blockIdx.x;
    const bf16_t* yrow = y + (size_t)row * 4096;
    const float* fQ = wfQ + row * N_NEU;
    const float* fK = wfK + row * N_NEU;
    const float* fV = wfV + row * N_NEU;
    float aQ = 0.f, aK = 0.f, aV = 0.f;
#pragma unroll
    for (int n = 0; n < N_NEU; n++) {
        float yq = (float)yrow[n * R_DIM + r];
        float yv = (float)yrow[2048 + n * R_DIM + r];
        aQ += fQ[n] * yq;
        aK += fK[n] * yq;
        aV += fV[n] * yv;
    }
    const float* rQ = wrQ + row * N_NEU;
    const float* rK = wrK + row * N_NEU;
    const float* rV = wrV + row * N_NEU;
    const size_t rb = (size_t)row * 2048;
#pragma unroll
    for (int n = 0; n < N_NEU; n++) {
        sq[rb + n * R_DIM + r] = (bf16_t)(rQ[n] * aQ);
        sk[rb + n * R_DIM + r] = (bf16_t)(rK[n] * aK);
        sv[rb + n * R_DIM + r] = (bf16_t)(rV[n] * aV);
    }
}

// know-path ws with fused split-K reduce (bf16 partials), KR=128.
__global__ __launch_bounds__(256)
void ws2_kernel(const bf16_t* __restrict__ P0, const bf16_t* __restrict__ P1,
                const float* __restrict__ wf, const float* __restrict__ wr,
                bf16_t* __restrict__ sout)
{
    const int lr = threadIdx.x >> 7;
    const int r  = threadIdx.x & 127;
    const int row = blockIdx.x * 2 + lr;
    const size_t rb = (size_t)row * (N_NEU * KR_DIM);
    const float* wfp = wf + row * N_NEU;
    const float* wrp = wr + row * N_NEU;
    float acc = 0.f;
#pragma unroll
    for (int n = 0; n < N_NEU; n++) {
        size_t i = rb + n * KR_DIM + r;
        acc += wfp[n] * ((float)P0[i] + (float)P1[i]);
    }
    bf16_t* srow = sout + rb;
#pragma unroll
    for (int n = 0; n < N_NEU; n++) srow[n * KR_DIM + r] = (bf16_t)(wrp[n] * acc);
}

// ---------------------------------------------------------------------------
// GEMM, 3-buffer counted-vmcnt pipeline (T3+T4) + T2 LDS XOR-swizzle.
// Swizzle: within each 64B row, colbyte ^= ((row&6)<<3).  Applied to the
// GLOBAL source of global_load_lds (LDS dest stays linear, rule #21) and to
// the ds_read address.  8-way bank conflict -> 2-way (free).
// C[M,N] = A[M,K] @ Bsel[N,K]^T.  128x128 tile, BK=32.
// EPI=0: bf16 C.  EPI=1: fp32 C = acc + resid.  EPI=2: bf16 partial per
// blockIdx.z (split-K=2) at Cout + z*M*N.
// ---------------------------------------------------------------------------
template<int EPI>
__global__ __launch_bounds__(256)
void gemm_kernel(const bf16_t* __restrict__ A, const bf16_t* __restrict__ Bt,
                 const bf16_t* __restrict__ Bt2, int splitMy,
                 void* Cout, const float* resid, int M, int N, int K)
{
    __shared__ bf16_t As[3][128][32];
    __shared__ bf16_t Bs[3][128][32];
    const int tid = threadIdx.x;
    const int l = tid & 63, w = tid >> 6;
    const int wr = w >> 1, wc = w & 1;

    // XCD-chunked swizzle (bijective when grid multiple of 8)
    const int nbxy = gridDim.x * gridDim.y;
    int bid = blockIdx.y * gridDim.x + blockIdx.x;
    if ((nbxy & 7) == 0) bid = (bid & 7) * (nbxy >> 3) + (bid >> 3);
    const int bx = bid % gridDim.x, by = bid / gridDim.x;

    const int m0 = by * 128, n0 = bx * 128;
    const bf16_t* Bsel = (by < splitMy) ? Bt : Bt2;

    int kbeg = 0, kend = K;
    if constexpr (EPI == 2) { const int half = K >> 1; kbeg = blockIdx.z * half; kend = kbeg + half; }

    // staging: lane l covers LDS bytes [chunkbase + l*16, +16) (linear).
    // LDS row = l>>2 (within 16-row chunk), colbyte = (l&3)*16.
    // Global source column pre-swizzled: colbyte ^ ((row&6)<<3).
    const int srow = l >> 2;
    const int scolswz = (((l & 3) * 16) ^ ((srow & 6) << 3)) >> 1;   // elements
    const bf16_t* Ag0 = A    + (size_t)(m0 + w * 32 + srow) * K + scolswz;
    const bf16_t* Ag1 = Ag0 + (size_t)16 * K;
    const bf16_t* Bg0 = Bsel + (size_t)(n0 + w * 32 + srow) * K + scolswz;
    const bf16_t* Bg1 = Bg0 + (size_t)16 * K;

    auto stage = [&](int buf, int k0) {
        char* Asb = (char*)&As[buf][0][0] + w * 2048;
        char* Bsb = (char*)&Bs[buf][0][0] + w * 2048;
        gl_lds16(Ag0 + k0, Asb);
        gl_lds16(Ag1 + k0, Asb + 1024);
        gl_lds16(Bg0 + k0, Bsb);
        gl_lds16(Bg1 + k0, Bsb + 1024);
    };

    f32x4 acc[4][4];
    const f32x4 zero = {0.f, 0.f, 0.f, 0.f};
#pragma unroll
    for (int i = 0; i < 4; i++)
#pragma unroll
        for (int j = 0; j < 4; j++) acc[i][j] = zero;

    const int fr = l & 15;
    const int fkb = (l >> 4) * 16;    // frag col byte: 0,16,32,48

    // prologue: stage tiles 0 and 1 (all our K >= 512, nK >= 16)
    stage(0, kbeg);
    stage(1, kbeg + 32);

    const int nK = (kend - kbeg) >> 5;
    for (int it = 0; it < nK; ++it) {
        if (it + 1 < nK) {
            asm volatile("s_waitcnt vmcnt(4)" ::: "memory");
        } else {
            asm volatile("s_waitcnt vmcnt(0)" ::: "memory");
        }
        __builtin_amdgcn_s_barrier();
        __builtin_amdgcn_sched_barrier(0);   // pin: nothing crosses the barrier

        const int cur = it % 3;
        const char* Ab = (const char*)&As[cur][0][0];
        const char* Bb = (const char*)&Bs[cur][0][0];
        bf16x8 af[4], bv[4];
#pragma unroll
        for (int i = 0; i < 4; i++) {
            const int rowA = wr * 64 + i * 16 + fr;
            af[i] = *(const bf16x8*)(Ab + rowA * 64 + (fkb ^ ((rowA & 6) << 3)));
        }
#pragma unroll
        for (int i = 0; i < 4; i++) {
            const int rowB = wc * 64 + i * 16 + fr;
            bv[i] = *(const bf16x8*)(Bb + rowB * 64 + (fkb ^ ((rowB & 6) << 3)));
        }

        if (it + 2 < nK) stage((it + 2) % 3, kbeg + (it + 2) * 32);

        __builtin_amdgcn_s_setprio(1);
#pragma unroll
        for (int mi = 0; mi < 4; mi++)
#pragma unroll
            for (int ni = 0; ni < 4; ni++)
                acc[mi][ni] = __builtin_amdgcn_mfma_f32_16x16x32_bf16(af[mi], bv[ni], acc[mi][ni], 0, 0, 0);
        __builtin_amdgcn_s_setprio(0);
    }

    const int orow = (l >> 4) * 4;
    const int ocol = l & 15;
#pragma unroll
    for (int mi = 0; mi < 4; mi++)
#pragma unroll
        for (int ni = 0; ni < 4; ni++)
#pragma unroll
            for (int j = 0; j < 4; j++) {
                int row = m0 + wr * 64 + mi * 16 + orow + j;
                int col = n0 + wc * 64 + ni * 16 + ocol;
                size_t idx = (size_t)row * N + col;
                if constexpr (EPI == 0) {
                    ((bf16_t*)Cout)[idx] = (bf16_t)acc[mi][ni][j];
                } else if constexpr (EPI == 1) {
                    ((float*)Cout)[idx] = acc[mi][ni][j] + resid[idx];
                } else {
                    ((bf16_t*)Cout)[(size_t)blockIdx.z * M * N + idx] = (bf16_t)acc[mi][ni][j];
                }
            }
}

// ---------------------------------------------------------------------------
// Causal flash attention, KVBLK=128 (two fused 64-key sub-tiles).
// (unchanged from R9)
// ---------------------------------------------------------------------------
__global__ __launch_bounds__(256)
void fa_kernel(const bf16_t* __restrict__ Q, const bf16_t* __restrict__ K,
               const bf16_t* __restrict__ Vt, bf16_t* __restrict__ O)
{
    __shared__ bf16_t Ks[128][72];
    __shared__ bf16_t Vs[64][136];
    __shared__ bf16_t Ps[4][16][136];

    const int tid = threadIdx.x;
    const int l = tid & 63, w = tid >> 6;

    const int bid  = blockIdx.x;
    const int xcd  = bid & 7;
    const int slot = bid >> 3;          // 0..63
    const int head = slot & 3;
    const int jq   = slot >> 2;         // 0..15
    const int bh   = xcd * 4 + head;
    const int b = bh >> 4, h = bh & 15;

    const bf16_t* Qp = Q + (size_t)b * S_LEN * D_DIM + h * DH;
    const bf16_t* Kp = K + (size_t)b * S_LEN * D_DIM + h * DH;
    const bf16_t* Vp = Vt + (size_t)b * D_DIM * S_LEN + (size_t)h * DH * S_LEN;

    const int fr = l & 15, fg = l >> 4, fk = fg * 8;
    const int srow = tid >> 2;          // 0..63
    const int scol = (tid & 3) * 16;    // 0,16,32,48
    const bf16_t* Kst = Kp + (size_t)srow * D_DIM + scol;
    const bf16_t* Vst = Vp + (size_t)srow * S_LEN + scol;

    bf16x8 ones8;
#pragma unroll
    for (int i = 0; i < 8; i++) ones8[i] = (bf16_t)1.f;

    const f32x4 zero = {0.f, 0.f, 0.f, 0.f};
    const float C_LOG2 = 0.125f * 1.44269504f;   // 1/sqrt(DH) * log2(e)

    for (int pass = 0; pass < 2; ++pass) {
        const int qb = pass ? jq : (31 - jq);    // long pass first
        const int q0 = qb * 64;
        const int nt = (qb >> 1) + 1;            // 128-key tiles

        bf16x8 qf[2];
#pragma unroll
        for (int ks = 0; ks < 2; ks++)
            qf[ks] = *(const bf16x8*)(Qp + (size_t)(q0 + w * 16 + fr) * D_DIM + ks * 32 + fk);

        f32x4 o[4];
        f32x4 la = zero;
        float m_r[4];
#pragma unroll
        for (int j = 0; j < 4; j++) { o[j] = zero; m_r[j] = -1e30f; }

        // prologue: issue loads for tile 0 (keys 0..127; rows always in-bounds)
        uint4 kva = *(const uint4*)(Kst);
        uint4 kvb = *(const uint4*)(Kst + 8);
        uint4 kvc = *(const uint4*)(Kst + (size_t)64 * D_DIM);
        uint4 kvd = *(const uint4*)(Kst + (size_t)64 * D_DIM + 8);
        uint4 vva = *(const uint4*)(Vst);
        uint4 vvb = *(const uint4*)(Vst + 8);
        uint4 vvc = *(const uint4*)(Vst + 64);
        uint4 vvd = *(const uint4*)(Vst + 72);

        for (int t = 0; t < nt; t++) {
            const int k0 = t * 128;
            __syncthreads();              // previous tile's reads complete
            *(uint4*)&Ks[srow][scol]          = kva;
            *(uint4*)&Ks[srow][scol + 8]      = kvb;
            *(uint4*)&Ks[64 + srow][scol]     = kvc;
            *(uint4*)&Ks[64 + srow][scol + 8] = kvd;
            *(uint4*)&Vs[srow][scol]          = vva;
            *(uint4*)&Vs[srow][scol + 8]      = vvb;
            *(uint4*)&Vs[srow][64 + scol]     = vvc;
            *(uint4*)&Vs[srow][64 + scol + 8] = vvd;
            __syncthreads();

            if (t + 1 < nt) {             // T14: issue next tile's loads now
                const int kn = k0 + 128;
                kva = *(const uint4*)(Kst + (size_t)kn * D_DIM);
                kvb = *(const uint4*)(Kst + (size_t)kn * D_DIM + 8);
                kvc = *(const uint4*)(Kst + (size_t)(kn + 64) * D_DIM);
                kvd = *(const uint4*)(Kst + (size_t)(kn + 64) * D_DIM + 8);
                vva = *(const uint4*)(Vst + kn);
                vvb = *(const uint4*)(Vst + kn + 8);
                vvc = *(const uint4*)(Vst + kn + 64);
                vvd = *(const uint4*)(Vst + kn + 72);
            }

            // ---- QK^T: 16 q-rows x 128 keys (2 independent sub-tiles) ----
            f32x4 sc[2][4];
#pragma unroll
            for (int s2 = 0; s2 < 2; s2++)
#pragma unroll
                for (int ni = 0; ni < 4; ni++) sc[s2][ni] = zero;
            __builtin_amdgcn_s_setprio(1);
#pragma unroll
            for (int ks = 0; ks < 2; ks++) {
#pragma unroll
                for (int s2 = 0; s2 < 2; s2++)
#pragma unroll
                    for (int ni = 0; ni < 4; ni++) {
                        bf16x8 kf = *(const bf16x8*)&Ks[s2 * 64 + ni * 16 + fr][ks * 32 + fk];
                        sc[s2][ni] = __builtin_amdgcn_mfma_f32_16x16x32_bf16(qf[ks], kf, sc[s2][ni], 0, 0, 0);
                    }
            }
            __builtin_amdgcn_s_setprio(0);

            // ---- scale to log2 domain (+ causal mask only on last tile) ----
            float p[2][4][4];
            if (t == nt - 1) {
#pragma unroll
                for (int s2 = 0; s2 < 2; s2++)
#pragma unroll
                    for (int ni = 0; ni < 4; ni++) {
                        const int key = k0 + s2 * 64 + ni * 16 + fr;
#pragma unroll
                        for (int j = 0; j < 4; j++) {
                            const int qg = q0 + w * 16 + fg * 4 + j;
                            p[s2][ni][j] = (key <= qg) ? sc[s2][ni][j] * C_LOG2 : -1e30f;
                        }
                    }
            } else {
#pragma unroll
                for (int s2 = 0; s2 < 2; s2++)
#pragma unroll
                    for (int ni = 0; ni < 4; ni++)
#pragma unroll
                        for (int j = 0; j < 4; j++)
                            p[s2][ni][j] = sc[s2][ni][j] * C_LOG2;
            }

            // ---- online softmax over 128 keys (one tree per tile) ----
#pragma unroll
            for (int j = 0; j < 4; j++) {
                float rmax = p[0][0][j];
#pragma unroll
                for (int s2 = 0; s2 < 2; s2++)
#pragma unroll
                    for (int ni = 0; ni < 4; ni++) rmax = fmaxf(rmax, p[s2][ni][j]);
#pragma unroll
                for (int d = 1; d < 16; d <<= 1) rmax = fmaxf(rmax, __shfl_xor(rmax, d));
                if (rmax > m_r[j] + 8.f) {         // defer-max (T13)
                    float scale = exp2f(m_r[j] - rmax);
                    la[j] *= scale;
#pragma unroll
                    for (int nc = 0; nc < 4; nc++) o[nc][j] *= scale;
                    m_r[j] = rmax;
                }
#pragma unroll
                for (int s2 = 0; s2 < 2; s2++)
#pragma unroll
                    for (int ni = 0; ni < 4; ni++)
                        p[s2][ni][j] = exp2f(p[s2][ni][j] - m_r[j]);   // <= 2^8
            }

            // ---- P -> A-layout via per-wave LDS bounce (128 cols) ----
#pragma unroll
            for (int s2 = 0; s2 < 2; s2++)
#pragma unroll
                for (int ni = 0; ni < 4; ni++)
#pragma unroll
                    for (int j = 0; j < 4; j++)
                        Ps[w][fg * 4 + j][s2 * 64 + ni * 16 + fr] = (bf16_t)p[s2][ni][j];

            // ---- PV + l-sum over 128 keys (4 ks steps) ----
            __builtin_amdgcn_s_setprio(1);
#pragma unroll
            for (int ks = 0; ks < 4; ks++) {
                bf16x8 pa = *(const bf16x8*)&Ps[w][fr][ks * 32 + fk];
                la = __builtin_amdgcn_mfma_f32_16x16x32_bf16(pa, ones8, la, 0, 0, 0);
#pragma unroll
                for (int nc = 0; nc < 4; nc++) {
                    bf16x8 vf = *(const bf16x8*)&Vs[nc * 16 + fr][ks * 32 + fk];
                    o[nc] = __builtin_amdgcn_mfma_f32_16x16x32_bf16(pa, vf, o[nc], 0, 0, 0);
                }
            }
            __builtin_amdgcn_s_setprio(0);
        }

        // ---- epilogue for this q-tile ----
#pragma unroll
        for (int j = 0; j < 4; j++) {
            const float inv = 1.f / la[j];
            const int q = q0 + w * 16 + fg * 4 + j;
            bf16_t* op = O + (size_t)(b * S_LEN + q) * D_DIM + h * DH;
#pragma unroll
            for (int nc = 0; nc < 4; nc++)
                op[nc * 16 + fr] = (bf16_t)(o[nc][j] * inv);
        }
    }
}

// ---------------------------------------------------------------------------
extern "C" void kernel_launch(void* const* d_in, const int* in_sizes, int n_in,
                              void* d_out, int out_size, void* d_ws, size_t ws_size,
                              hipStream_t stream)
{
    const float* x      = (const float*)d_in[0];
    const float* fqk_wQ = (const float*)d_in[1];
    const float* fqk_wK = (const float*)d_in[2];
    const float* fv_w   = (const float*)d_in[3];
    const float* rqk_wQ = (const float*)d_in[4];
    const float* rqk_wK = (const float*)d_in[5];
    const float* rv_w   = (const float*)d_in[6];
    const float* fkn_w  = (const float*)d_in[7];
    const float* rkn_w  = (const float*)d_in[8];
    const float* f_qk   = (const float*)d_in[9];
    const float* f_v    = (const float*)d_in[10];
    const float* r_qk   = (const float*)d_in[11];
    const float* r_v    = (const float*)d_in[12];
    const float* f_know = (const float*)d_in[13];
    const float* r_know = (const float*)d_in[14];
    const float* W_O    = (const float*)d_in[15];
    const float* ln1g   = (const float*)d_in[16];
    const float* ln1b   = (const float*)d_in[17];
    const float* ln2g   = (const float*)d_in[18];
    const float* ln2b   = (const float*)d_in[19];
    float* out_f = (float*)d_out;
    (void)ws_size; (void)in_sizes; (void)n_in; (void)out_size;

    // ---- workspace layout (reused slots) ----
    char* ws = (char*)d_ws;
    const size_t MB = 1024 * 1024;
    bf16_t* rqkT   = (bf16_t*)(ws + 0 * MB);    // [1024][2048]  4MB
    bf16_t* rvT    = (bf16_t*)(ws + 4 * MB);    // [1024][2048]  4MB
    bf16_t* rknT   = (bf16_t*)(ws + 8 * MB);    // [1024][1024]  2MB
    bf16_t* woB    = (bf16_t*)(ws + 10 * MB);   // [1024][1024]  2MB
    bf16_t* fknT   = (bf16_t*)(ws + 12 * MB);   // [1024][1024]  2MB
    bf16_t* buf_nx = (bf16_t*)(ws + 14 * MB);   // 8MB: nx -> Vt -> nx2
    bf16_t* buf_y  = (bf16_t*)(ws + 22 * MB);   // 32MB: y[4096][4096] -> QKV[12288][1024]
    char*   buf_s  = ws + 54 * MB;              // 48MB
    bf16_t* fqkT   = (bf16_t*)(buf_s);               // [2048][1024] 4MB (pre-ws only)
    bf16_t* fvT    = (bf16_t*)(buf_s + 4 * MB);      // contiguous -> N=4096 B
    bf16_t* s_q    = (bf16_t*)(buf_s);               // [12288][2048] grouped A
    bf16_t* s_k    = (bf16_t*)(buf_s) + (size_t)4096 * 2048;
    bf16_t* s_v    = (bf16_t*)(buf_s) + (size_t)8192 * 2048;
    bf16_t* attn   = (bf16_t*)(buf_s);               // [4096][1024] 8MB
    bf16_t* P0     = (bf16_t*)(buf_s + 16 * MB);     // W_O bf16 partials 2x8MB [16,32MB)
    bf16_t* P0k    = (bf16_t*)(buf_s);               // know bf16 partials 2x8MB [0,16MB)
    bf16_t* sk2    = (bf16_t*)(buf_s + 32 * MB);     // [4096][1024] 8MB
    bf16_t* Qb     = buf_y;                          // QKV contiguous [12288][1024]
    bf16_t* Kb     = buf_y + (size_t)4096 * 1024;
    bf16_t* Vb     = buf_y + (size_t)8192 * 1024;
    bf16_t* Vt     = buf_nx;                         // [2][1024][2048]

    const dim3 blk256(256), blkT(32, 8);

    // ---- weight conversion ----
    tcast_kernel<<<dim3(R_DIM / 32, D_DIM / 32, N_NEU), blkT, 0, stream>>>(f_qk, fqkT, D_DIM, R_DIM);
    tcast_kernel<<<dim3(R_DIM / 32, D_DIM / 32, N_NEU), blkT, 0, stream>>>(f_v, fvT, D_DIM, R_DIM);
    tcast_kernel<<<dim3(KR_DIM / 32, D_DIM / 32, N_NEU), blkT, 0, stream>>>(f_know, fknT, D_DIM, KR_DIM);
    tcast_kernel<<<dim3(D_DIM / 32, 2048 / 32, 1), blkT, 0, stream>>>(r_qk, rqkT, 2048, D_DIM);
    tcast_kernel<<<dim3(D_DIM / 32, 2048 / 32, 1), blkT, 0, stream>>>(r_v, rvT, 2048, D_DIM);
    tcast_kernel<<<dim3(D_DIM / 32, 1024 / 32, 1), blkT, 0, stream>>>(r_know, rknT, 1024, D_DIM);
    cast_kernel<<<dim3(1024 * 1024 / 4 / 256), blk256, 0, stream>>>(W_O, woB, 1024 * 1024 / 4);

    // ---- LN1 ----
    ln_kernel<<<dim3(ROWS), blk256, 0, stream>>>(x, ln1g, ln1b, buf_nx);

    // ---- fused feature GEMM: y[4096][4096] = nx @ [fqkT;fvT]^T ----
    gemm_kernel<0><<<dim3(32, 32), blk256, 0, stream>>>(buf_nx, fqkT, fqkT, 1 << 30, buf_y, nullptr, 4096, 4096, 1024);

    // ---- fused weighted sums -> sq|sk|sv [12288][2048] ----
    wsf_kernel<<<dim3(ROWS), blk256, 0, stream>>>(buf_y, fqk_wQ, rqk_wQ, fqk_wK, rqk_wK, fv_w, rv_w, s_q, s_k, s_v);

    // ---- grouped restore GEMM: QKV[12288][1024] (768 blocks, B-select) ----
    gemm_kernel<0><<<dim3(8, 96), blk256, 0, stream>>>((bf16_t*)buf_s, rqkT, rvT, 64, buf_y, nullptr, 12288, 1024, 2048);

    // ---- V -> Vt ----
    tbf_kernel<<<dim3(D_DIM / 32, S_LEN / 32, B_DIM), blkT, 0, stream>>>(Vb, Vt, S_LEN, D_DIM);

    // ---- attention (512 balanced two-pass blocks, KVBLK=128) ----
    fa_kernel<<<dim3(512), blk256, 0, stream>>>(Qb, Kb, Vt, attn);

    // ---- W_O split-K=2: bf16 partials (512 blocks) ----
    gemm_kernel<2><<<dim3(8, 32, 2), blk256, 0, stream>>>(attn, woB, woB, 1 << 30, P0, nullptr, 4096, 1024, 1024);

    // ---- LN2 fused: d_out = x + P0 + P1; nx2 = LN(d_out) ----
    ln2x_kernel<<<dim3(ROWS), blk256, 0, stream>>>(x, P0, P0 + (size_t)4096 * 1024, ln2g, ln2b, out_f, buf_nx);

    // ---- know feature split-K=2: bf16 partials (512 blocks) ----
    gemm_kernel<2><<<dim3(8, 32, 2), blk256, 0, stream>>>(buf_nx, fknT, fknT, 1 << 30, P0k, nullptr, 4096, 1024, 1024);

    // ---- know ws (fused reduce) -> sk2 ----
    ws2_kernel<<<dim3(ROWS / 2), blk256, 0, stream>>>(P0k, P0k + (size_t)4096 * 1024, fkn_w, rkn_w, sk2);

    // ---- out = sk2 @ rknT^T + x2 -> d_out ----
    gemm_kernel<1><<<dim3(8, 32), blk256, 0, stream>>>(sk2, rknT, rknT, 1 << 30, d_out, out_f, 4096, 1024, 1024);
}